// Round 3
// baseline (12684.645 us; speedup 1.0000x reference)
//
#include <hip/hip_runtime.h>
#include <hip/hip_bf16.h>

typedef float  f32x4  __attribute__((ext_vector_type(4)));
typedef short  short8 __attribute__((ext_vector_type(8)));
typedef short  bf4    __attribute__((ext_vector_type(4)));

#define MFMA16(a,b,c) __builtin_amdgcn_mfma_f32_16x16x32_bf16((a),(b),(c),0,0,0)

__device__ __forceinline__ short tobf(float f){
  unsigned u = __float_as_uint(f);
  u += 0x7fffu + ((u >> 16) & 1u);
  return (short)(u >> 16);
}
__device__ __forceinline__ float frombf(short s){
  return __uint_as_float(((unsigned)(unsigned short)s) << 16);
}
__device__ __forceinline__ float sigf(float x){
  return 1.f / (1.f + __expf(-x));
}
__device__ __forceinline__ float tanhf_(float x){
  float ax = fabsf(x);
  float e  = __expf(-2.f * ax);
  float t  = (1.f - e) / (1.f + e);
  return x >= 0.f ? t : -t;
}
__device__ __forceinline__ bf4 pack4(f32x4 v){
  bf4 r; r[0]=tobf(v[0]); r[1]=tobf(v[1]); r[2]=tobf(v[2]); r[3]=tobf(v[3]); return r;
}

// LDS h-tile: [32 rows][256 cols] bf16, XOR-swizzled 16B slots (G4).
__device__ __forceinline__ int hoff(int row, int col){
  return (row*512 + col*2) ^ ((row & 7) << 4);
}
__device__ __forceinline__ void stH(short* buf, int row, int col, short v){
  *(short*)((char*)buf + hoff(row,col)) = v;
}
__device__ __forceinline__ short ldH(const short* buf, int row, int col){
  return *(const short*)((const char*)buf + hoff(row,col));
}
// A-fragment (16x32 tile): lane holds A[row=l&15][k0 + (l>>4)*8 + j]
__device__ __forceinline__ short8 ldA(const short* buf, int rt, int k0, int lane){
  int row = rt*16 + (lane & 15);
  int off = (row*512 + (k0 + ((lane>>4)<<3))*2) ^ ((row & 7) << 4);
  return *(const short8*)((const char*)buf + off);
}
// B-fragment from pre-swizzled weights: 1KB per (nt,kt) tile, lane-contiguous
__device__ __forceinline__ short8 ldB(const short* wsz, int nt, int KT, int kt, int lane){
  return *(const short8*)(wsz + (((nt*KT + kt)*64 + lane) << 3));
}

// Pre-swizzle fp32 weight [N][K] slice into bf16 B-fragments
__global__ void swz_kernel(short* __restrict__ dst, const float* __restrict__ src,
                           int rowStride, int colOff, int Nreal,
                           int KTtot, int kt0, int ktN, int NT){
  int idx = blockIdx.x*256 + threadIdx.x;
  if (idx >= NT*ktN*512) return;
  int j = idx & 7, l = (idx>>3) & 63, tile = idx >> 9;
  int nt = tile / ktN, ktl = tile - nt*ktN;
  int n = nt*16 + (l & 15);
  int k = ktl*32 + ((l>>4)<<3) + j;
  float v = (n < Nreal) ? src[n*rowStride + colOff + k] : 0.f;
  dst[(((nt*KTtot + kt0 + ktl)*64 + l)<<3) + j] = tobf(v);
}

// eprojb[s][v][g] = bf16( emb[s][v] @ W1_ih[s][:, :256].T + b1_ih[s] + b1_hh[s] )
__global__ __launch_bounds__(1024) void eproj_kernel(
    const float* __restrict__ emb, const float* __restrict__ b1_ih,
    const float* __restrict__ b1_hh, const short* __restrict__ W1ihA_s,
    short* __restrict__ eprojb){
  __shared__ short es[36864];     // [144][256] bf16, rows >=130 zero
  const int s = blockIdx.x;
  const int tid = threadIdx.x, lane = tid & 63, w = tid >> 6;
  const int l15 = lane & 15, lg = lane >> 4;
  for (int idx = tid; idx < 36864; idx += 1024){
    int row = idx >> 8, c2 = idx & 255;
    float v = (row < 130) ? emb[(s*130 + row)*256 + c2] : 0.f;
    stH(es, row, c2, tobf(v));
  }
  __syncthreads();
  f32x4 z4 = {0.f,0.f,0.f,0.f};
  for (int rt = 0; rt < 9; ++rt){
    f32x4 acc[4] = {z4, z4, z4, z4};
    #pragma unroll 2
    for (int kt = 0; kt < 8; ++kt){
      short8 a = ldA(es, rt, kt*32, lane);
      #pragma unroll
      for (int q = 0; q < 4; ++q){
        short8 b = ldB(W1ihA_s + s*262144, w*4 + q, 8, kt, lane);
        acc[q] = MFMA16(a, b, acc[q]);
      }
    }
    #pragma unroll
    for (int q = 0; q < 4; ++q)
      #pragma unroll
      for (int r = 0; r < 4; ++r){
        int v = rt*16 + lg*4 + r;
        if (v < 130){
          int gc = (w*4 + q)*16 + l15;
          eprojb[(s*130 + v)*1024 + gc] =
            tobf(acc[q][r] + b1_ih[s*1024 + gc] + b1_hh[s*1024 + gc]);
        }
      }
  }
}

// Main persistent kernel: one WG per (bar, batch-chunk-of-32). 1024 threads,
// 16 waves (4/SIMD for latency hiding). Wave w owns hidden block hb=w:
// gate tiles nt = g*16+w, columns cc = w*16+l15 of each 256-wide gate slice.
__global__ __launch_bounds__(1024, 4) void rnn_main(
    const float* __restrict__ cbuf, const int* __restrict__ tgt,
    const float* __restrict__ b_hid, const float* __restrict__ b1_ih,
    const float* __restrict__ b1_hh, const float* __restrict__ bc_ih,
    const float* __restrict__ bc_hh, const float* __restrict__ boutp,
    const short* __restrict__ eprojb,
    const short* __restrict__ W1hh_s, const short* __restrict__ W1ihA_s,
    const short* __restrict__ W1ihB_s, const short* __restrict__ Wc_s,
    const short* __restrict__ Whid_s, const short* __restrict__ Wout_s,
    float* __restrict__ outp)
{
  __shared__ short h1b[3][8192];
  __shared__ short h2b[3][8192];
  __shared__ short hcb[8192];
  __shared__ short hsb[8192];     // scratch: c staging at reset, h1+h2 otherwise

  const int tid  = threadIdx.x;
  const int lane = tid & 63;
  const int w    = tid >> 6;      // wave 0..15 = hidden block
  const int l15  = lane & 15;
  const int lg   = lane >> 4;
  const int chunk = blockIdx.x;   // 0..3
  const int bar   = blockIdx.y;   // 0..15
  const int b0    = chunk * 32;
  const int cc    = w*16 + l15;   // column within each 256-wide gate slice

  float c1s[3][2][4];             // [stream][rt][r]
  float c2s[3][2][4];
  float ccs[2][4];
  bf4   cpb[3][2][4];             // c_t @ W1_ihB contribution, [s][rt][g]

  const f32x4 z4 = {0.f,0.f,0.f,0.f};

  for (int tt = 0; tt < 16; ++tt){
    const int t = bar*16 + tt;

    if (tt == 0){
      // R1: stage bf16(c[:,bar]) into hsb
      for (int idx = tid; idx < 8192; idx += 1024){
        int row = idx >> 8, c2 = idx & 255;
        stH(hsb, row, c2, tobf(cbuf[((b0+row)*17 + bar)*256 + c2]));
      }
      __syncthreads();
      // R2K: h_init = tanh(c_bar @ W_hid[:256].T + b_hid[:256]); wave w -> nt=w
      f32x4 hi0 = z4, hi1 = z4;
      #pragma unroll
      for (int kt = 0; kt < 8; ++kt){
        short8 a0 = ldA(hsb, 0, kt*32, lane);
        short8 a1 = ldA(hsb, 1, kt*32, lane);
        short8 bb = ldB(Whid_s, w, 8, kt, lane);
        hi0 = MFMA16(a0, bb, hi0);  hi1 = MFMA16(a1, bb, hi1);
      }
      __syncthreads();
      // R2elem: h_init into all 7 h-buffers; zero c-states
      {
        float bh = b_hid[cc];
        #pragma unroll
        for (int rt = 0; rt < 2; ++rt)
          #pragma unroll
          for (int r = 0; r < 4; ++r){
            int row = rt*16 + lg*4 + r;
            short hv = tobf(tanhf_((rt ? hi1[r] : hi0[r]) + bh));
            stH(h1b[0],row,cc,hv); stH(h1b[1],row,cc,hv); stH(h1b[2],row,cc,hv);
            stH(h2b[0],row,cc,hv); stH(h2b[1],row,cc,hv); stH(h2b[2],row,cc,hv);
            stH(hcb,  row,cc,hv);
          }
      }
      #pragma unroll
      for (int s = 0; s < 3; ++s)
        #pragma unroll
        for (int rt = 0; rt < 2; ++rt)
          #pragma unroll
          for (int r = 0; r < 4; ++r){ c1s[s][rt][r] = 0.f; c2s[s][rt][r] = 0.f; }
      #pragma unroll
      for (int rt = 0; rt < 2; ++rt)
        #pragma unroll
        for (int r = 0; r < 4; ++r) ccs[rt][r] = 0.f;
      // R3: stage bf16(c[:,bar+1]) into hsb
      for (int idx = tid; idx < 8192; idx += 1024){
        int row = idx >> 8, c2 = idx & 255;
        stH(hsb, row, c2, tobf(cbuf[((b0+row)*17 + bar + 1)*256 + c2]));
      }
      __syncthreads();
      // R4: cpb[s] = c_t @ W1_ih[s][:,256:].T  (registers, merged 3 streams)
      {
        f32x4 acc[3][2][4];
        #pragma unroll
        for (int s = 0; s < 3; ++s)
          #pragma unroll
          for (int rt = 0; rt < 2; ++rt)
            #pragma unroll
            for (int g = 0; g < 4; ++g) acc[s][rt][g] = z4;
        #pragma unroll
        for (int kt = 0; kt < 8; ++kt){
          short8 a0 = ldA(hsb, 0, kt*32, lane);
          short8 a1 = ldA(hsb, 1, kt*32, lane);
          #pragma unroll
          for (int s = 0; s < 3; ++s)
            #pragma unroll
            for (int g = 0; g < 4; ++g){
              short8 bb = ldB(W1ihB_s + s*262144, g*16 + w, 8, kt, lane);
              acc[s][0][g] = MFMA16(a0, bb, acc[s][0][g]);
              acc[s][1][g] = MFMA16(a1, bb, acc[s][1][g]);
            }
        }
        #pragma unroll
        for (int s = 0; s < 3; ++s)
          #pragma unroll
          for (int rt = 0; rt < 2; ++rt)
            #pragma unroll
            for (int g = 0; g < 4; ++g) cpb[s][rt][g] = pack4(acc[s][rt][g]);
      }
      // h1b writes fenced by post-R3 barrier; R4 touches no LDS writes.
    }

    // ---------- Stage A: lstm1 first update, all 3 streams merged ----------
    {
      f32x4 acc[3][2][4];
      #pragma unroll
      for (int s = 0; s < 3; ++s)
        #pragma unroll
        for (int rt = 0; rt < 2; ++rt)
          #pragma unroll
          for (int g = 0; g < 4; ++g) acc[s][rt][g] = z4;
      #pragma unroll
      for (int kt = 0; kt < 8; ++kt){
        #pragma unroll
        for (int s = 0; s < 3; ++s){
          short8 a0 = ldA(h1b[s], 0, kt*32, lane);
          short8 a1 = ldA(h1b[s], 1, kt*32, lane);
          #pragma unroll
          for (int g = 0; g < 4; ++g){
            short8 bb = ldB(W1hh_s + s*262144, g*16 + w, 8, kt, lane);
            acc[s][0][g] = MFMA16(a0, bb, acc[s][0][g]);
            acc[s][1][g] = MFMA16(a1, bb, acc[s][1][g]);
          }
        }
      }
      __syncthreads();
      #pragma unroll
      for (int s = 0; s < 3; ++s)
        #pragma unroll
        for (int rt = 0; rt < 2; ++rt)
          #pragma unroll
          for (int r = 0; r < 4; ++r){
            const int row = rt*16 + lg*4 + r;
            const int tok = (t == 0) ? 0 : tgt[(s*128 + b0 + row)*256 + (t-1)];
            const short* ep = eprojb + (s*130 + tok)*1024;
            float pi = acc[s][rt][0][r] + frombf(ep[cc])     + frombf(cpb[s][rt][0][r]);
            float pf = acc[s][rt][1][r] + frombf(ep[256+cc]) + frombf(cpb[s][rt][1][r]);
            float pg = acc[s][rt][2][r] + frombf(ep[512+cc]) + frombf(cpb[s][rt][2][r]);
            float po = acc[s][rt][3][r] + frombf(ep[768+cc]) + frombf(cpb[s][rt][3][r]);
            float cs = c1s[s][rt][r];
            cs = sigf(pf)*cs + sigf(pi)*tanhf_(pg);
            c1s[s][rt][r] = cs;
            stH(h1b[s], row, cc, tobf(sigf(po)*tanhf_(cs)));
          }
      __syncthreads();
    }

    // ---------- per-stream sequential section ----------
    #pragma unroll
    for (int i = 0; i < 3; ++i){
      // ---- B: context lstm_c (K=1024 over [h1_0,h1_1,h1_2,hc])
      {
        f32x4 acc[2][4];
        #pragma unroll
        for (int rt = 0; rt < 2; ++rt)
          #pragma unroll
          for (int g = 0; g < 4; ++g) acc[rt][g] = z4;
        #pragma unroll
        for (int seg = 0; seg < 4; ++seg){
          const short* hbuf = (seg==0) ? h1b[0] : (seg==1) ? h1b[1] : (seg==2) ? h1b[2] : hcb;
          #pragma unroll
          for (int ktl = 0; ktl < 8; ++ktl){
            const int kt = seg*8 + ktl;
            short8 a0 = ldA(hbuf, 0, ktl*32, lane);
            short8 a1 = ldA(hbuf, 1, ktl*32, lane);
            #pragma unroll
            for (int g = 0; g < 4; ++g){
              short8 bb = ldB(Wc_s, g*16 + w, 32, kt, lane);
              acc[0][g] = MFMA16(a0, bb, acc[0][g]);
              acc[1][g] = MFMA16(a1, bb, acc[1][g]);
            }
          }
        }
        __syncthreads();
        const float bi = bc_ih[cc]      + bc_hh[cc];
        const float bf = bc_ih[256+cc]  + bc_hh[256+cc];
        const float bg = bc_ih[512+cc]  + bc_hh[512+cc];
        const float bo = bc_ih[768+cc]  + bc_hh[768+cc];
        #pragma unroll
        for (int rt = 0; rt < 2; ++rt)
          #pragma unroll
          for (int r = 0; r < 4; ++r){
            const int row = rt*16 + lg*4 + r;
            float pi = acc[rt][0][r] + bi;
            float pf = acc[rt][1][r] + bf;
            float pg = acc[rt][2][r] + bg;
            float po = acc[rt][3][r] + bo;
            float cs = ccs[rt][r];
            cs = sigf(pf)*cs + sigf(pi)*tanhf_(pg);
            ccs[rt][r] = cs;
            stH(hcb, row, cc, tobf(sigf(po)*tanhf_(cs)));
          }
        __syncthreads();
      }
      // ---- C: lstm2 (K=256 from hc with W1ihA + K=256 from h2 with W1hh)
      {
        f32x4 acc[2][4];
        #pragma unroll
        for (int rt = 0; rt < 2; ++rt)
          #pragma unroll
          for (int g = 0; g < 4; ++g) acc[rt][g] = z4;
        #pragma unroll
        for (int kt = 0; kt < 8; ++kt){
          short8 a0 = ldA(hcb, 0, kt*32, lane);
          short8 a1 = ldA(hcb, 1, kt*32, lane);
          #pragma unroll
          for (int g = 0; g < 4; ++g){
            short8 bb = ldB(W1ihA_s + i*262144, g*16 + w, 8, kt, lane);
            acc[0][g] = MFMA16(a0, bb, acc[0][g]);
            acc[1][g] = MFMA16(a1, bb, acc[1][g]);
          }
        }
        #pragma unroll
        for (int kt = 0; kt < 8; ++kt){
          short8 a0 = ldA(h2b[i], 0, kt*32, lane);
          short8 a1 = ldA(h2b[i], 1, kt*32, lane);
          #pragma unroll
          for (int g = 0; g < 4; ++g){
            short8 bb = ldB(W1hh_s + i*262144, g*16 + w, 8, kt, lane);
            acc[0][g] = MFMA16(a0, bb, acc[0][g]);
            acc[1][g] = MFMA16(a1, bb, acc[1][g]);
          }
        }
        __syncthreads();
        const float bi = b1_ih[i*1024+cc]      + b1_hh[i*1024+cc];
        const float bf = b1_ih[i*1024+256+cc]  + b1_hh[i*1024+256+cc];
        const float bg = b1_ih[i*1024+512+cc]  + b1_hh[i*1024+512+cc];
        const float bo = b1_ih[i*1024+768+cc]  + b1_hh[i*1024+768+cc];
        #pragma unroll
        for (int rt = 0; rt < 2; ++rt)
          #pragma unroll
          for (int r = 0; r < 4; ++r){
            const int row = rt*16 + lg*4 + r;
            float pi = acc[rt][0][r] + bi + frombf(cpb[i][rt][0][r]);
            float pf = acc[rt][1][r] + bf + frombf(cpb[i][rt][1][r]);
            float pg = acc[rt][2][r] + bg + frombf(cpb[i][rt][2][r]);
            float po = acc[rt][3][r] + bo + frombf(cpb[i][rt][3][r]);
            float cs = c2s[i][rt][r];
            cs = sigf(pf)*cs + sigf(pi)*tanhf_(pg);
            c2s[i][rt][r] = cs;
            float hn = sigf(po)*tanhf_(cs);
            stH(h2b[i], row, cc, tobf(hn));
            float h1o = frombf(ldH(h1b[i], row, cc));
            stH(hsb, row, cc, tobf(h1o + hn));
          }
        __syncthreads();
      }
      // ---- ED: lstm1 second update GEMM (D) + output projection (E)
      {
        f32x4 dacc[2][4];
        #pragma unroll
        for (int rt = 0; rt < 2; ++rt)
          #pragma unroll
          for (int g = 0; g < 4; ++g) dacc[rt][g] = z4;
        #pragma unroll
        for (int kt = 0; kt < 8; ++kt){
          short8 a0 = ldA(h1b[i], 0, kt*32, lane);
          short8 a1 = ldA(h1b[i], 1, kt*32, lane);
          #pragma unroll
          for (int g = 0; g < 4; ++g){
            short8 bb = ldB(W1hh_s + i*262144, g*16 + w, 8, kt, lane);
            dacc[0][g] = MFMA16(a0, bb, dacc[0][g]);
            dacc[1][g] = MFMA16(a1, bb, dacc[1][g]);
          }
        }
        f32x4 e0 = z4, e1 = z4;
        if (w < 9){
          #pragma unroll
          for (int kt = 0; kt < 8; ++kt){
            short8 a0 = ldA(hsb, 0, kt*32, lane);
            short8 a1 = ldA(hsb, 1, kt*32, lane);
            short8 bb = ldB(Wout_s + i*36864, w, 8, kt, lane);
            e0 = MFMA16(a0, bb, e0);  e1 = MFMA16(a1, bb, e1);
          }
        }
        __syncthreads();
        // D elem: teacher-forced notes update of lstm1
        #pragma unroll
        for (int rt = 0; rt < 2; ++rt)
          #pragma unroll
          for (int r = 0; r < 4; ++r){
            const int row = rt*16 + lg*4 + r;
            const int tok = tgt[(i*128 + b0 + row)*256 + t];
            const short* ep = eprojb + (i*130 + tok)*1024;
            float pi = dacc[rt][0][r] + frombf(ep[cc])     + frombf(cpb[i][rt][0][r]);
            float pf = dacc[rt][1][r] + frombf(ep[256+cc]) + frombf(cpb[i][rt][1][r]);
            float pg = dacc[rt][2][r] + frombf(ep[512+cc]) + frombf(cpb[i][rt][2][r]);
            float po = dacc[rt][3][r] + frombf(ep[768+cc]) + frombf(cpb[i][rt][3][r]);
            float cs = c1s[i][rt][r];
            cs = sigf(pf)*cs + sigf(pi)*tanhf_(pg);
            c1s[i][rt][r] = cs;
            stH(h1b[i], row, cc, tobf(sigf(po)*tanhf_(cs)));
          }
        // E store: logits (v = w*16+l15 valid while < 130)
        if (w < 8){
          const int v = w*16 + l15;
          const float bo = boutp[i*130 + v];
          #pragma unroll
          for (int rt = 0; rt < 2; ++rt)
            #pragma unroll
            for (int r = 0; r < 4; ++r){
              const int row = rt*16 + lg*4 + r;
              outp[(size_t)((i*128 + b0 + row)*256 + t)*130 + v] = (rt ? e1[r] : e0[r]) + bo;
            }
        } else if (w == 8 && l15 < 2){
          const int v = 128 + l15;
          const float bo = boutp[i*130 + v];
          #pragma unroll
          for (int rt = 0; rt < 2; ++rt)
            #pragma unroll
            for (int r = 0; r < 4; ++r){
              const int row = rt*16 + lg*4 + r;
              outp[(size_t)((i*128 + b0 + row)*256 + t)*130 + v] = (rt ? e1[r] : e0[r]) + bo;
            }
        }
        __syncthreads();
      }
    } // i
  } // tt
}

extern "C" void kernel_launch(void* const* d_in, const int* in_sizes, int n_in,
                              void* d_out, int out_size, void* d_ws, size_t ws_size,
                              hipStream_t stream){
  (void)in_sizes; (void)n_in; (void)out_size; (void)ws_size;
  const float* c     = (const float*)d_in[0];
  const int*   tgt   = (const int*)  d_in[1];
  const float* W_hid = (const float*)d_in[3];
  const float* b_hid = (const float*)d_in[4];
  const float* W1_ih = (const float*)d_in[5];
  const float* W1_hh = (const float*)d_in[6];
  const float* b1_ih = (const float*)d_in[7];
  const float* b1_hh = (const float*)d_in[8];
  const float* Wc_ih = (const float*)d_in[9];
  const float* Wc_hh = (const float*)d_in[10];
  const float* bc_ih = (const float*)d_in[11];
  const float* bc_hh = (const float*)d_in[12];
  const float* emb   = (const float*)d_in[13];
  const float* Wout  = (const float*)d_in[14];
  const float* bout  = (const float*)d_in[15];
  float* outp = (float*)d_out;

  short* ws = (short*)d_ws;
  short* W1hh_s  = ws;                 // 3 x 64nt x 8kt tiles
  short* W1ihA_s = ws + 786432;        // W1_ih[:, :256]
  short* W1ihB_s = ws + 1572864;       // W1_ih[:, 256:512]
  short* Wc_s    = ws + 2359296;       // [1024][1024]: ih k<768, hh k>=768
  short* Whid_s  = ws + 3407872;       // [256][256]
  short* Wout_s  = ws + 3473408;       // 3 x [144 pad][256]
  short* eprojb  = ws + 3584000;       // [3][130][1024] bf16

  for (int s = 0; s < 3; ++s){
    swz_kernel<<<1024,256,0,stream>>>(W1hh_s  + s*262144, W1_hh + s*262144, 256,   0, 1024,  8, 0,  8, 64);
    swz_kernel<<<1024,256,0,stream>>>(W1ihA_s + s*262144, W1_ih + s*524288, 512,   0, 1024,  8, 0,  8, 64);
    swz_kernel<<<1024,256,0,stream>>>(W1ihB_s + s*262144, W1_ih + s*524288, 512, 256, 1024,  8, 0,  8, 64);
    swz_kernel<<< 144,256,0,stream>>>(Wout_s  + s*36864,  Wout  + s*33280,  256,   0,  130,  8, 0,  8,  9);
  }
  swz_kernel<<<3072,256,0,stream>>>(Wc_s,   Wc_ih, 768, 0, 1024, 32,  0, 24, 64);
  swz_kernel<<<1024,256,0,stream>>>(Wc_s,   Wc_hh, 256, 0, 1024, 32, 24,  8, 64);
  swz_kernel<<< 256,256,0,stream>>>(Whid_s, W_hid, 256, 0,  512,  8,  0,  8, 16);
  eproj_kernel<<<3,1024,0,stream>>>(emb, b1_ih, b1_hh, W1ihA_s, eprojb);

  rnn_main<<<dim3(4,16),1024,0,stream>>>(c, tgt, b_hid, b1_ih, b1_hh, bc_ih, bc_hh,
                                         bout, eprojb, W1hh_s, W1ihA_s, W1ihB_s,
                                         Wc_s, Whid_s, Wout_s, outp);
}

// Round 5
// 11028.934 us; speedup vs baseline: 1.1501x; 1.1501x over previous
//
#include <hip/hip_runtime.h>
#include <hip/hip_bf16.h>

typedef float  f32x4  __attribute__((ext_vector_type(4)));
typedef short  short8 __attribute__((ext_vector_type(8)));
typedef short  bf4    __attribute__((ext_vector_type(4)));

#define MFMA16(a,b,c) __builtin_amdgcn_mfma_f32_16x16x32_bf16((a),(b),(c),0,0,0)

__device__ __forceinline__ short tobf(float f){
  unsigned u = __float_as_uint(f);
  u += 0x7fffu + ((u >> 16) & 1u);
  return (short)(u >> 16);
}
__device__ __forceinline__ float frombf(short s){
  return __uint_as_float(((unsigned)(unsigned short)s) << 16);
}
__device__ __forceinline__ float sigf(float x){
  return 1.f / (1.f + __expf(-x));
}
__device__ __forceinline__ float tanhf_(float x){
  float ax = fabsf(x);
  float e  = __expf(-2.f * ax);
  float t  = (1.f - e) / (1.f + e);
  return x >= 0.f ? t : -t;
}
__device__ __forceinline__ bf4 pack4(f32x4 v){
  bf4 r; r[0]=tobf(v[0]); r[1]=tobf(v[1]); r[2]=tobf(v[2]); r[3]=tobf(v[3]); return r;
}

// LDS h-tile: [32 rows][256 cols] bf16, XOR-swizzled 16B slots (G4).
__device__ __forceinline__ int hoff(int row, int col){
  return (row*512 + col*2) ^ ((row & 7) << 4);
}
__device__ __forceinline__ void stH(short* buf, int row, int col, short v){
  *(short*)((char*)buf + hoff(row,col)) = v;
}
// A-fragment (16x32 tile): lane holds A[row=l&15][k0 + (l>>4)*8 + j]
__device__ __forceinline__ short8 ldA(const short* buf, int rt, int k0, int lane){
  int row = rt*16 + (lane & 15);
  int off = (row*512 + (k0 + ((lane>>4)<<3))*2) ^ ((row & 7) << 4);
  return *(const short8*)((const char*)buf + off);
}
// B-fragment from pre-swizzled weights: 1KB per (nt,kt) tile, lane-contiguous
__device__ __forceinline__ short8 ldB(const short* wsz, int nt, int KT, int kt, int lane){
  return *(const short8*)(wsz + (((nt*KT + kt)*64 + lane) << 3));
}
// cpart C-fragment layout: per WG [s][w][rt*4+g][lane*4 + r] bf16
__device__ __forceinline__ short* cpPtr(short* cp, int s, int w, int rt, int g, int lane){
  return cp + (((s*16 + w)*8 + rt*4 + g) << 8) + (lane << 2);
}
__device__ __forceinline__ f32x4 ldCP(const short* cp, int s, int w, int rt, int g, int lane){
  bf4 v = *(const bf4*)(cp + (((s*16 + w)*8 + rt*4 + g) << 8) + (lane << 2));
  f32x4 r; r[0]=frombf(v[0]); r[1]=frombf(v[1]); r[2]=frombf(v[2]); r[3]=frombf(v[3]);
  return r;
}

// Pre-swizzle fp32 weight [N][K] slice into bf16 B-fragments
__global__ void swz_kernel(short* __restrict__ dst, const float* __restrict__ src,
                           int rowStride, int colOff, int Nreal,
                           int KTtot, int kt0, int ktN, int NT){
  int idx = blockIdx.x*256 + threadIdx.x;
  if (idx >= NT*ktN*512) return;
  int j = idx & 7, l = (idx>>3) & 63, tile = idx >> 9;
  int nt = tile / ktN, ktl = tile - nt*ktN;
  int n = nt*16 + (l & 15);
  int k = ktl*32 + ((l>>4)<<3) + j;
  float v = (n < Nreal) ? src[n*rowStride + colOff + k] : 0.f;
  dst[(((nt*KTtot + kt0 + ktl)*64 + l)<<3) + j] = tobf(v);
}

// eprojb[s][v][g] = bf16( emb[s][v] @ W1_ih[s][:, :256].T + b1_ih[s] + b1_hh[s] )
__global__ __launch_bounds__(1024) void eproj_kernel(
    const float* __restrict__ emb, const float* __restrict__ b1_ih,
    const float* __restrict__ b1_hh, const short* __restrict__ W1ihA_s,
    short* __restrict__ eprojb){
  __shared__ short es[36864];     // [144][256] bf16, rows >=130 zero
  const int s = blockIdx.x;
  const int tid = threadIdx.x, lane = tid & 63, w = tid >> 6;
  const int l15 = lane & 15, lg = lane >> 4;
  for (int idx = tid; idx < 36864; idx += 1024){
    int row = idx >> 8, c2 = idx & 255;
    float v = (row < 130) ? emb[(s*130 + row)*256 + c2] : 0.f;
    stH(es, row, c2, tobf(v));
  }
  __syncthreads();
  f32x4 z4 = {0.f,0.f,0.f,0.f};
  for (int rt = 0; rt < 9; ++rt){
    f32x4 acc[4] = {z4, z4, z4, z4};
    #pragma unroll 2
    for (int kt = 0; kt < 8; ++kt){
      short8 a = ldA(es, rt, kt*32, lane);
      #pragma unroll
      for (int q = 0; q < 4; ++q){
        short8 b = ldB(W1ihA_s + s*262144, w*4 + q, 8, kt, lane);
        acc[q] = MFMA16(a, b, acc[q]);
      }
    }
    #pragma unroll
    for (int q = 0; q < 4; ++q)
      #pragma unroll
      for (int r = 0; r < 4; ++r){
        int v = rt*16 + lg*4 + r;
        if (v < 130){
          int gc = (w*4 + q)*16 + l15;
          eprojb[(s*130 + v)*1024 + gc] =
            tobf(acc[q][r] + b1_ih[s*1024 + gc] + b1_hh[s*1024 + gc]);
        }
      }
  }
}

// Main persistent kernel: one WG per (bar, batch-chunk-of-32). 1024 threads,
// 16 waves (exactly 4/SIMD, 128 regs). Wave w owns gate-col block cc=w*16+l15.
// Low-pressure phase design: one acc[2][4] per GEMM phase; cpart lives in
// global ws in C-fragment layout and seeds the accumulators (not registers).
__global__ __launch_bounds__(1024)
__attribute__((amdgpu_waves_per_eu(4,4))) void rnn_main(
    const float* __restrict__ cbuf, const int* __restrict__ tgt,
    const float* __restrict__ b_hid, const float* __restrict__ b1_ih,
    const float* __restrict__ b1_hh, const float* __restrict__ bc_ih,
    const float* __restrict__ bc_hh, const float* __restrict__ boutp,
    const short* __restrict__ eprojb, short* __restrict__ cpart,
    const short* __restrict__ W1hh_s, const short* __restrict__ W1ihA_s,
    const short* __restrict__ W1ihB_s, const short* __restrict__ Wc_s,
    const short* __restrict__ Whid_s, const short* __restrict__ Wout_s,
    float* __restrict__ outp)
{
  __shared__ short h1b[3][8192];
  __shared__ short h2b[3][8192];
  __shared__ short hcb[8192];

  const int tid  = threadIdx.x;
  const int lane = tid & 63;
  const int w    = tid >> 6;      // wave 0..15
  const int l15  = lane & 15;
  const int lg   = lane >> 4;
  const int chunk = blockIdx.x;   // 0..3
  const int bar   = blockIdx.y;   // 0..15
  const int b0    = chunk * 32;
  const int cc    = w*16 + l15;

  float c1s[3][2][4];             // persistent cell states: 56 f32 total
  float c2s[3][2][4];
  float ccs[2][4];

  short* cpWG = cpart + (bar*4 + chunk)*98304;
  const f32x4 z4 = {0.f,0.f,0.f,0.f};

  for (int tt = 0; tt < 16; ++tt){
    const int t = bar*16 + tt;

    if (tt == 0){
      // R1/R3: stage bf16(c[:,bar]) into h2b[0], bf16(c[:,bar+1]) into h2b[1]
      for (int idx = tid; idx < 8192; idx += 1024){
        int row = idx >> 8, c2 = idx & 255;
        stH(h2b[0], row, c2, tobf(cbuf[((b0+row)*17 + bar)*256 + c2]));
        stH(h2b[1], row, c2, tobf(cbuf[((b0+row)*17 + bar + 1)*256 + c2]));
      }
      __syncthreads();
      // R2K: h_init pre-activation (c_bar @ W_hid[:256].T), wave w -> nt=w
      f32x4 hi0 = z4, hi1 = z4;
      #pragma unroll
      for (int kt = 0; kt < 8; ++kt){
        short8 a0 = ldA(h2b[0], 0, kt*32, lane);
        short8 a1 = ldA(h2b[0], 1, kt*32, lane);
        short8 bb = ldB(Whid_s, w, 8, kt, lane);
        hi0 = MFMA16(a0, bb, hi0);  hi1 = MFMA16(a1, bb, hi1);
      }
      // R4: cpart[s] = c_t @ W1_ih[s][:,256:].T -> global ws (C-frag layout)
      #pragma unroll
      for (int s = 0; s < 3; ++s){
        f32x4 acc[2][4];
        #pragma unroll
        for (int rt = 0; rt < 2; ++rt)
          #pragma unroll
          for (int g = 0; g < 4; ++g) acc[rt][g] = z4;
        #pragma unroll
        for (int kt = 0; kt < 8; ++kt){
          short8 a0 = ldA(h2b[1], 0, kt*32, lane);
          short8 a1 = ldA(h2b[1], 1, kt*32, lane);
          #pragma unroll
          for (int g = 0; g < 4; ++g){
            short8 bb = ldB(W1ihB_s + s*262144, g*16 + w, 8, kt, lane);
            acc[0][g] = MFMA16(a0, bb, acc[0][g]);
            acc[1][g] = MFMA16(a1, bb, acc[1][g]);
          }
        }
        #pragma unroll
        for (int rt = 0; rt < 2; ++rt)
          #pragma unroll
          for (int g = 0; g < 4; ++g)
            *(bf4*)cpPtr(cpWG, s, w, rt, g, lane) = pack4(acc[rt][g]);
      }
      __syncthreads();
      // R2elem: h_init into all 7 h-buffers (clobbers staging); zero c-states
      {
        float bh = b_hid[cc];
        #pragma unroll
        for (int rt = 0; rt < 2; ++rt)
          #pragma unroll
          for (int r = 0; r < 4; ++r){
            int row = rt*16 + lg*4 + r;
            short hv = tobf(tanhf_((rt ? hi1[r] : hi0[r]) + bh));
            stH(h1b[0],row,cc,hv); stH(h1b[1],row,cc,hv); stH(h1b[2],row,cc,hv);
            stH(h2b[0],row,cc,hv); stH(h2b[1],row,cc,hv); stH(h2b[2],row,cc,hv);
            stH(hcb,  row,cc,hv);
          }
      }
      #pragma unroll
      for (int s = 0; s < 3; ++s)
        #pragma unroll
        for (int rt = 0; rt < 2; ++rt)
          #pragma unroll
          for (int r = 0; r < 4; ++r){ c1s[s][rt][r] = 0.f; c2s[s][rt][r] = 0.f; }
      #pragma unroll
      for (int rt = 0; rt < 2; ++rt)
        #pragma unroll
        for (int r = 0; r < 4; ++r) ccs[rt][r] = 0.f;
      __syncthreads();
    }

    // ---------- Stage A: per-stream phases; elem(s) overlaps gemm(s+1) ----
    #pragma unroll
    for (int s = 0; s < 3; ++s){
      f32x4 acc[2][4];
      #pragma unroll
      for (int rt = 0; rt < 2; ++rt)
        #pragma unroll
        for (int g = 0; g < 4; ++g) acc[rt][g] = ldCP(cpWG, s, w, rt, g, lane);
      #pragma unroll
      for (int kt = 0; kt < 8; ++kt){
        short8 a0 = ldA(h1b[s], 0, kt*32, lane);
        short8 a1 = ldA(h1b[s], 1, kt*32, lane);
        #pragma unroll
        for (int g = 0; g < 4; ++g){
          short8 bb = ldB(W1hh_s + s*262144, g*16 + w, 8, kt, lane);
          acc[0][g] = MFMA16(a0, bb, acc[0][g]);
          acc[1][g] = MFMA16(a1, bb, acc[1][g]);
        }
      }
      __syncthreads();   // protect h1b[s] read-before-write
      #pragma unroll
      for (int rt = 0; rt < 2; ++rt)
        #pragma unroll
        for (int r = 0; r < 4; ++r){
          const int row = rt*16 + lg*4 + r;
          const int tok = (t == 0) ? 0 : tgt[(s*128 + b0 + row)*256 + (t-1)];
          const short* ep = eprojb + (s*130 + tok)*1024;
          float pi = acc[rt][0][r] + frombf(ep[cc]);
          float pf = acc[rt][1][r] + frombf(ep[256+cc]);
          float pg = acc[rt][2][r] + frombf(ep[512+cc]);
          float po = acc[rt][3][r] + frombf(ep[768+cc]);
          float cs = c1s[s][rt][r];
          cs = sigf(pf)*cs + sigf(pi)*tanhf_(pg);
          c1s[s][rt][r] = cs;
          stH(h1b[s], row, cc, tobf(sigf(po)*tanhf_(cs)));
        }
      // no barrier: next iteration's gemm reads h1b[s+1], disjoint from h1b[s]
    }
    __syncthreads();     // h1b[0..2] complete before B reads them

    // ---------- per-stream sequential section ----------
    #pragma unroll
    for (int i = 0; i < 3; ++i){
      // ---- Bg: context lstm_c GEMM (K=1024 over [h1_0,h1_1,h1_2,hc])
      {
        f32x4 acc[2][4];
        #pragma unroll
        for (int rt = 0; rt < 2; ++rt)
          #pragma unroll
          for (int g = 0; g < 4; ++g) acc[rt][g] = z4;
        #pragma unroll
        for (int seg = 0; seg < 4; ++seg){
          const short* hbuf = (seg==0) ? h1b[0] : (seg==1) ? h1b[1] : (seg==2) ? h1b[2] : hcb;
          #pragma unroll
          for (int ktl = 0; ktl < 8; ++ktl){
            const int kt = seg*8 + ktl;
            short8 a0 = ldA(hbuf, 0, ktl*32, lane);
            short8 a1 = ldA(hbuf, 1, ktl*32, lane);
            #pragma unroll
            for (int g = 0; g < 4; ++g){
              short8 bb = ldB(Wc_s, g*16 + w, 32, kt, lane);
              acc[0][g] = MFMA16(a0, bb, acc[0][g]);
              acc[1][g] = MFMA16(a1, bb, acc[1][g]);
            }
          }
        }
        __syncthreads();
        // Be: hc update
        const float bi = bc_ih[cc]      + bc_hh[cc];
        const float bf = bc_ih[256+cc]  + bc_hh[256+cc];
        const float bg = bc_ih[512+cc]  + bc_hh[512+cc];
        const float bo = bc_ih[768+cc]  + bc_hh[768+cc];
        #pragma unroll
        for (int rt = 0; rt < 2; ++rt)
          #pragma unroll
          for (int r = 0; r < 4; ++r){
            const int row = rt*16 + lg*4 + r;
            float pi = acc[rt][0][r] + bi;
            float pf = acc[rt][1][r] + bf;
            float pg = acc[rt][2][r] + bg;
            float po = acc[rt][3][r] + bo;
            float cs = ccs[rt][r];
            cs = sigf(pf)*cs + sigf(pi)*tanhf_(pg);
            ccs[rt][r] = cs;
            stH(hcb, row, cc, tobf(sigf(po)*tanhf_(cs)));
          }
        __syncthreads();
      }
      // ---- Cg: lstm2 GEMM (hc @ W1ihA + h2 @ W1hh), acc seeded with cpart
      {
        f32x4 acc[2][4];
        #pragma unroll
        for (int rt = 0; rt < 2; ++rt)
          #pragma unroll
          for (int g = 0; g < 4; ++g) acc[rt][g] = ldCP(cpWG, i, w, rt, g, lane);
        #pragma unroll
        for (int kt = 0; kt < 8; ++kt){
          short8 a0 = ldA(hcb, 0, kt*32, lane);
          short8 a1 = ldA(hcb, 1, kt*32, lane);
          #pragma unroll
          for (int g = 0; g < 4; ++g){
            short8 bb = ldB(W1ihA_s + i*262144, g*16 + w, 8, kt, lane);
            acc[0][g] = MFMA16(a0, bb, acc[0][g]);
            acc[1][g] = MFMA16(a1, bb, acc[1][g]);
          }
        }
        #pragma unroll
        for (int kt = 0; kt < 8; ++kt){
          short8 a0 = ldA(h2b[i], 0, kt*32, lane);
          short8 a1 = ldA(h2b[i], 1, kt*32, lane);
          #pragma unroll
          for (int g = 0; g < 4; ++g){
            short8 bb = ldB(W1hh_s + i*262144, g*16 + w, 8, kt, lane);
            acc[0][g] = MFMA16(a0, bb, acc[0][g]);
            acc[1][g] = MFMA16(a1, bb, acc[1][g]);
          }
        }
        __syncthreads();
        // Ce: c2/h2 update
        const float bi = b1_ih[i*1024+cc]      + b1_hh[i*1024+cc];
        const float bf = b1_ih[i*1024+256+cc]  + b1_hh[i*1024+256+cc];
        const float bg = b1_ih[i*1024+512+cc]  + b1_hh[i*1024+512+cc];
        const float bo = b1_ih[i*1024+768+cc]  + b1_hh[i*1024+768+cc];
        #pragma unroll
        for (int rt = 0; rt < 2; ++rt)
          #pragma unroll
          for (int r = 0; r < 4; ++r){
            const int row = rt*16 + lg*4 + r;
            float pi = acc[rt][0][r] + bi;
            float pf = acc[rt][1][r] + bf;
            float pg = acc[rt][2][r] + bg;
            float po = acc[rt][3][r] + bo;
            float cs = c2s[i][rt][r];
            cs = sigf(pf)*cs + sigf(pi)*tanhf_(pg);
            c2s[i][rt][r] = cs;
            stH(h2b[i], row, cc, tobf(sigf(po)*tanhf_(cs)));
          }
        __syncthreads();
      }
      // ---- DEg: D GEMM (h1 @ W1hh, seeded with cpart) + E GEMM ((h1+h2)@Wout)
      {
        f32x4 dacc[2][4];
        #pragma unroll
        for (int rt = 0; rt < 2; ++rt)
          #pragma unroll
          for (int g = 0; g < 4; ++g) dacc[rt][g] = ldCP(cpWG, i, w, rt, g, lane);
        f32x4 e0 = z4, e1 = z4;
        #pragma unroll
        for (int kt = 0; kt < 8; ++kt){
          short8 a0 = ldA(h1b[i], 0, kt*32, lane);
          short8 a1 = ldA(h1b[i], 1, kt*32, lane);
          #pragma unroll
          for (int g = 0; g < 4; ++g){
            short8 bb = ldB(W1hh_s + i*262144, g*16 + w, 8, kt, lane);
            dacc[0][g] = MFMA16(a0, bb, dacc[0][g]);
            dacc[1][g] = MFMA16(a1, bb, dacc[1][g]);
          }
          if (w < 9){
            short8 bb = ldB(Wout_s + i*36864, w, 8, kt, lane);
            short8 b0f = ldA(h2b[i], 0, kt*32, lane);
            short8 b1f = ldA(h2b[i], 1, kt*32, lane);
            e0 = MFMA16(a0, bb, e0);  e0 = MFMA16(b0f, bb, e0);
            e1 = MFMA16(a1, bb, e1);  e1 = MFMA16(b1f, bb, e1);
          }
        }
        __syncthreads();
        // DEe: teacher-forced lstm1 update + logits store
        #pragma unroll
        for (int rt = 0; rt < 2; ++rt)
          #pragma unroll
          for (int r = 0; r < 4; ++r){
            const int row = rt*16 + lg*4 + r;
            const int tok = tgt[(i*128 + b0 + row)*256 + t];
            const short* ep = eprojb + (i*130 + tok)*1024;
            float pi = dacc[rt][0][r] + frombf(ep[cc]);
            float pf = dacc[rt][1][r] + frombf(ep[256+cc]);
            float pg = dacc[rt][2][r] + frombf(ep[512+cc]);
            float po = dacc[rt][3][r] + frombf(ep[768+cc]);
            float cs = c1s[i][rt][r];
            cs = sigf(pf)*cs + sigf(pi)*tanhf_(pg);
            c1s[i][rt][r] = cs;
            stH(h1b[i], row, cc, tobf(sigf(po)*tanhf_(cs)));
          }
        if (w < 8){
          const int v = w*16 + l15;
          const float bo = boutp[i*130 + v];
          #pragma unroll
          for (int rt = 0; rt < 2; ++rt)
            #pragma unroll
            for (int r = 0; r < 4; ++r){
              const int row = rt*16 + lg*4 + r;
              outp[(size_t)((i*128 + b0 + row)*256 + t)*130 + v] = (rt ? e1[r] : e0[r]) + bo;
            }
        } else if (w == 8 && l15 < 2){
          const int v = 128 + l15;
          const float bo = boutp[i*130 + v];
          #pragma unroll
          for (int rt = 0; rt < 2; ++rt)
            #pragma unroll
            for (int r = 0; r < 4; ++r){
              const int row = rt*16 + lg*4 + r;
              outp[(size_t)((i*128 + b0 + row)*256 + t)*130 + v] = (rt ? e1[r] : e0[r]) + bo;
            }
        }
        __syncthreads();
      }
    } // i
  } // tt
}

extern "C" void kernel_launch(void* const* d_in, const int* in_sizes, int n_in,
                              void* d_out, int out_size, void* d_ws, size_t ws_size,
                              hipStream_t stream){
  (void)in_sizes; (void)n_in; (void)out_size; (void)ws_size;
  const float* c     = (const float*)d_in[0];
  const int*   tgt   = (const int*)  d_in[1];
  const float* W_hid = (const float*)d_in[3];
  const float* b_hid = (const float*)d_in[4];
  const float* W1_ih = (const float*)d_in[5];
  const float* W1_hh = (const float*)d_in[6];
  const float* b1_ih = (const float*)d_in[7];
  const float* b1_hh = (const float*)d_in[8];
  const float* Wc_ih = (const float*)d_in[9];
  const float* Wc_hh = (const float*)d_in[10];
  const float* bc_ih = (const float*)d_in[11];
  const float* bc_hh = (const float*)d_in[12];
  const float* emb   = (const float*)d_in[13];
  const float* Wout  = (const float*)d_in[14];
  const float* bout  = (const float*)d_in[15];
  float* outp = (float*)d_out;

  short* ws = (short*)d_ws;
  short* W1hh_s  = ws;                 // 3 x 64nt x 8kt tiles
  short* W1ihA_s = ws + 786432;        // W1_ih[:, :256]
  short* W1ihB_s = ws + 1572864;       // W1_ih[:, 256:512]
  short* Wc_s    = ws + 2359296;       // [1024][1024]: ih k<768, hh k>=768
  short* Whid_s  = ws + 3407872;       // [256][256]
  short* Wout_s  = ws + 3473408;       // 3 x [144 pad][256]
  short* eprojb  = ws + 3584000;       // [3][130][1024] bf16
  short* cpart   = ws + 3983360;       // [64 WG][3][16][8][256] bf16 C-frags

  for (int s = 0; s < 3; ++s){
    swz_kernel<<<1024,256,0,stream>>>(W1hh_s  + s*262144, W1_hh + s*262144, 256,   0, 1024,  8, 0,  8, 64);
    swz_kernel<<<1024,256,0,stream>>>(W1ihA_s + s*262144, W1_ih + s*524288, 512,   0, 1024,  8, 0,  8, 64);
    swz_kernel<<<1024,256,0,stream>>>(W1ihB_s + s*262144, W1_ih + s*524288, 512, 256, 1024,  8, 0,  8, 64);
    swz_kernel<<< 144,256,0,stream>>>(Wout_s  + s*36864,  Wout  + s*33280,  256,   0,  130,  8, 0,  8,  9);
  }
  swz_kernel<<<3072,256,0,stream>>>(Wc_s,   Wc_ih, 768, 0, 1024, 32,  0, 24, 64);
  swz_kernel<<<1024,256,0,stream>>>(Wc_s,   Wc_hh, 256, 0, 1024, 32, 24,  8, 64);
  swz_kernel<<< 256,256,0,stream>>>(Whid_s, W_hid, 256, 0,  512,  8,  0,  8, 16);
  eproj_kernel<<<3,1024,0,stream>>>(emb, b1_ih, b1_hh, W1ihA_s, eprojb);

  rnn_main<<<dim3(4,16),1024,0,stream>>>(c, tgt, b_hid, b1_ih, b1_hh, bc_ih, bc_hh,
                                         bout, eprojb, cpart, W1hh_s, W1ihA_s, W1ihB_s,
                                         Wc_s, Whid_s, Wout_s, outp);
}

// Round 6
// 7957.311 us; speedup vs baseline: 1.5941x; 1.3860x over previous
//
#include <hip/hip_runtime.h>
#include <hip/hip_bf16.h>

typedef float  f32x4  __attribute__((ext_vector_type(4)));
typedef short  short8 __attribute__((ext_vector_type(8)));
typedef short  bf4    __attribute__((ext_vector_type(4)));

#define MFMA16(a,b,c) __builtin_amdgcn_mfma_f32_16x16x32_bf16((a),(b),(c),0,0,0)

__device__ __forceinline__ short tobf(float f){
  unsigned u = __float_as_uint(f);
  u += 0x7fffu + ((u >> 16) & 1u);
  return (short)(u >> 16);
}
__device__ __forceinline__ float frombf(short s){
  return __uint_as_float(((unsigned)(unsigned short)s) << 16);
}
__device__ __forceinline__ float sigf(float x){
  return 1.f / (1.f + __expf(-x));
}
__device__ __forceinline__ float tanhf_(float x){
  float ax = fabsf(x);
  float e  = __expf(-2.f * ax);
  float t  = (1.f - e) / (1.f + e);
  return x >= 0.f ? t : -t;
}
__device__ __forceinline__ bf4 pack4(f32x4 v){
  bf4 r; r[0]=tobf(v[0]); r[1]=tobf(v[1]); r[2]=tobf(v[2]); r[3]=tobf(v[3]); return r;
}

// LDS h-tile: [32 rows][256 cols] bf16, XOR-swizzled 16B slots (G4).
__device__ __forceinline__ int hoff(int row, int col){
  return (row*512 + col*2) ^ ((row & 7) << 4);
}
__device__ __forceinline__ void stH(short* buf, int row, int col, short v){
  *(short*)((char*)buf + hoff(row,col)) = v;
}
// A-fragment (16x32 tile): lane holds A[row=l&15][k0 + (l>>4)*8 + j]
__device__ __forceinline__ short8 ldA(const short* buf, int rt, int k0, int lane){
  int row = rt*16 + (lane & 15);
  int off = (row*512 + (k0 + ((lane>>4)<<3))*2) ^ ((row & 7) << 4);
  return *(const short8*)((const char*)buf + off);
}
// B-fragment from pre-swizzled weights: 1KB per (nt,kt) tile, lane-contiguous
__device__ __forceinline__ short8 ldB(const short* wsz, int nt, int KT, int kt, int lane){
  return *(const short8*)(wsz + (((nt*KT + kt)*64 + lane) << 3));
}
// cpart C-fragment layout: per WG [s][w][rt*4+g][lane*4 + r] bf16
__device__ __forceinline__ short* cpPtr(short* cp, int s, int w, int rt, int g, int lane){
  return cp + (((s*16 + w)*8 + rt*4 + g) << 8) + (lane << 2);
}
__device__ __forceinline__ f32x4 ldCP(const short* cp, int s, int w, int rt, int g, int lane){
  bf4 v = *(const bf4*)(cp + (((s*16 + w)*8 + rt*4 + g) << 8) + (lane << 2));
  f32x4 r; r[0]=frombf(v[0]); r[1]=frombf(v[1]); r[2]=frombf(v[2]); r[3]=frombf(v[3]);
  return r;
}
// cell-state slices in global ws: per WG 14 slices x 1024 threads x f32x4
__device__ __forceinline__ f32x4 ldCS(const float* b, int sl, int tid){
  return *(const f32x4*)(b + sl*4096 + tid*4);
}
__device__ __forceinline__ void stCS(float* b, int sl, int tid, f32x4 v){
  *(f32x4*)(b + sl*4096 + tid*4) = v;
}

// Pre-swizzle fp32 weight [N][K] slice into bf16 B-fragments
__global__ void swz_kernel(short* __restrict__ dst, const float* __restrict__ src,
                           int rowStride, int colOff, int Nreal,
                           int KTtot, int kt0, int ktN, int NT){
  int idx = blockIdx.x*256 + threadIdx.x;
  if (idx >= NT*ktN*512) return;
  int j = idx & 7, l = (idx>>3) & 63, tile = idx >> 9;
  int nt = tile / ktN, ktl = tile - nt*ktN;
  int n = nt*16 + (l & 15);
  int k = ktl*32 + ((l>>4)<<3) + j;
  float v = (n < Nreal) ? src[n*rowStride + colOff + k] : 0.f;
  dst[(((nt*KTtot + kt0 + ktl)*64 + l)<<3) + j] = tobf(v);
}

// eprojb[s][v][g] = bf16( emb[s][v] @ W1_ih[s][:, :256].T + b1_ih[s] + b1_hh[s] )
__global__ __launch_bounds__(1024) void eproj_kernel(
    const float* __restrict__ emb, const float* __restrict__ b1_ih,
    const float* __restrict__ b1_hh, const short* __restrict__ W1ihA_s,
    short* __restrict__ eprojb){
  __shared__ short es[36864];     // [144][256] bf16, rows >=130 zero
  const int s = blockIdx.x;
  const int tid = threadIdx.x, lane = tid & 63, w = tid >> 6;
  const int l15 = lane & 15, lg = lane >> 4;
  for (int idx = tid; idx < 36864; idx += 1024){
    int row = idx >> 8, c2 = idx & 255;
    float v = (row < 130) ? emb[(s*130 + row)*256 + c2] : 0.f;
    stH(es, row, c2, tobf(v));
  }
  __syncthreads();
  f32x4 z4 = {0.f,0.f,0.f,0.f};
  for (int rt = 0; rt < 9; ++rt){
    f32x4 acc[4] = {z4, z4, z4, z4};
    #pragma unroll 2
    for (int kt = 0; kt < 8; ++kt){
      short8 a = ldA(es, rt, kt*32, lane);
      #pragma unroll
      for (int q = 0; q < 4; ++q){
        short8 b = ldB(W1ihA_s + s*262144, w*4 + q, 8, kt, lane);
        acc[q] = MFMA16(a, b, acc[q]);
      }
    }
    #pragma unroll
    for (int q = 0; q < 4; ++q)
      #pragma unroll
      for (int r = 0; r < 4; ++r){
        int v = rt*16 + lg*4 + r;
        if (v < 130){
          int gc = (w*4 + q)*16 + l15;
          eprojb[(s*130 + v)*1024 + gc] =
            tobf(acc[q][r] + b1_ih[s*1024 + gc] + b1_hh[s*1024 + gc]);
        }
      }
  }
}

// rotating chunk buffers (statically folded under #pragma unroll)
#define ROT3(K)  ((((K)%3)==0)?fb0:((((K)%3)==1)?fb1:fb2))
#define ROTE3(K) ((((K)%3)==0)?eb0:((((K)%3)==1)?eb1:eb2))

#define LDCH(BUF, WP, KT, KTI) do{ \
  (BUF)[0] = ldB((WP),      w, (KT), (KTI), lane); \
  (BUF)[1] = ldB((WP), 16 + w, (KT), (KTI), lane); \
  (BUF)[2] = ldB((WP), 32 + w, (KT), (KTI), lane); \
  (BUF)[3] = ldB((WP), 48 + w, (KT), (KTI), lane); }while(0)

#define MMCH(BUF, AB, KTI) do{ \
  short8 a0_ = ldA((AB), 0, (KTI)*32, lane); \
  short8 a1_ = ldA((AB), 1, (KTI)*32, lane); \
  acc[0][0]=MFMA16(a0_,(BUF)[0],acc[0][0]); acc[1][0]=MFMA16(a1_,(BUF)[0],acc[1][0]); \
  acc[0][1]=MFMA16(a0_,(BUF)[1],acc[0][1]); acc[1][1]=MFMA16(a1_,(BUF)[1],acc[1][1]); \
  acc[0][2]=MFMA16(a0_,(BUF)[2],acc[0][2]); acc[1][2]=MFMA16(a1_,(BUF)[2],acc[1][2]); \
  acc[0][3]=MFMA16(a0_,(BUF)[3],acc[0][3]); acc[1][3]=MFMA16(a1_,(BUF)[3],acc[1][3]); }while(0)

// Main persistent kernel: one WG per (bar, batch-chunk-of-32). 1024 threads,
// 16 waves (4/SIMD, 128-VGPR cap). Cell states live in global ws (coalesced
// f32x4 slices, prefetched at phase start); B-fragments use depth-2 rotating
// prefetch so ~8 weight loads stay in flight per wave.
__global__ __launch_bounds__(1024)
__attribute__((amdgpu_waves_per_eu(4,4))) void rnn_main(
    const float* __restrict__ cbuf, const int* __restrict__ tgt,
    const float* __restrict__ b_hid, const float* __restrict__ b1_ih,
    const float* __restrict__ b1_hh, const float* __restrict__ bc_ih,
    const float* __restrict__ bc_hh, const float* __restrict__ boutp,
    const short* __restrict__ eprojb, short* __restrict__ cpart,
    float* __restrict__ cst,
    const short* __restrict__ W1hh_s, const short* __restrict__ W1ihA_s,
    const short* __restrict__ W1ihB_s, const short* __restrict__ Wc_s,
    const short* __restrict__ Whid_s, const short* __restrict__ Wout_s,
    float* __restrict__ outp)
{
  __shared__ short h1b[3*8192];
  __shared__ short h2b[3*8192];
  __shared__ short hcb[8192];

  const int tid  = threadIdx.x;
  const int lane = tid & 63;
  const int w    = tid >> 6;      // wave 0..15
  const int l15  = lane & 15;
  const int lg   = lane >> 4;
  const int chunk = blockIdx.x;   // 0..3
  const int bar   = blockIdx.y;   // 0..15
  const int b0    = chunk * 32;
  const int cc    = w*16 + l15;
  const int wgid  = bar*4 + chunk;

  short* cpWG  = cpart + wgid*98304;
  float* cstWG = cst + (size_t)wgid*57344;   // 14 slices x 4096 floats
  const f32x4 z4 = {0.f,0.f,0.f,0.f};

  #pragma unroll 1
  for (int tt = 0; tt < 16; ++tt){
    const int t = bar*16 + tt;

    if (tt == 0){
      // stage bf16(c[:,bar]) into h2b[0], bf16(c[:,bar+1]) into h2b[1]
      for (int idx = tid; idx < 8192; idx += 1024){
        int row = idx >> 8, c2 = idx & 255;
        stH(h2b,        row, c2, tobf(cbuf[((b0+row)*17 + bar)*256 + c2]));
        stH(h2b + 8192, row, c2, tobf(cbuf[((b0+row)*17 + bar + 1)*256 + c2]));
      }
      __syncthreads();
      // R2K: h_init pre-activation (c_bar @ W_hid[:256].T), wave w -> nt=w
      f32x4 hi0 = z4, hi1 = z4;
      #pragma unroll
      for (int kt = 0; kt < 8; ++kt){
        short8 a0 = ldA(h2b, 0, kt*32, lane);
        short8 a1 = ldA(h2b, 1, kt*32, lane);
        short8 bb = ldB(Whid_s, w, 8, kt, lane);
        hi0 = MFMA16(a0, bb, hi0);  hi1 = MFMA16(a1, bb, hi1);
      }
      // R4: cpart[s] = c_t @ W1_ih[s][:,256:].T -> global ws (chunk-prefetched)
      #pragma unroll 1
      for (int s = 0; s < 3; ++s){
        const short* Wp = W1ihB_s + s*262144;
        f32x4 acc[2][4];
        #pragma unroll
        for (int rt = 0; rt < 2; ++rt)
          #pragma unroll
          for (int g = 0; g < 4; ++g) acc[rt][g] = z4;
        short8 fb0[4], fb1[4], fb2[4];
        LDCH(fb0, Wp, 8, 0); LDCH(fb1, Wp, 8, 1);
        #pragma unroll
        for (int kt = 0; kt < 8; ++kt){
          if (kt < 6) LDCH(ROT3(kt+2), Wp, 8, kt+2);
          MMCH(ROT3(kt), h2b + 8192, kt);
        }
        #pragma unroll
        for (int rt = 0; rt < 2; ++rt)
          #pragma unroll
          for (int g = 0; g < 4; ++g)
            *(bf4*)cpPtr(cpWG, s, w, rt, g, lane) = pack4(acc[rt][g]);
      }
      __syncthreads();
      // h_init into all 7 h-buffers (clobbers staging)
      {
        float bh = b_hid[cc];
        #pragma unroll
        for (int rt = 0; rt < 2; ++rt)
          #pragma unroll
          for (int r = 0; r < 4; ++r){
            int row = rt*16 + lg*4 + r;
            short hv = tobf(tanhf_((rt ? hi1[r] : hi0[r]) + bh));
            stH(h1b,       row,cc,hv); stH(h1b+8192, row,cc,hv); stH(h1b+16384,row,cc,hv);
            stH(h2b,       row,cc,hv); stH(h2b+8192, row,cc,hv); stH(h2b+16384,row,cc,hv);
            stH(hcb,       row,cc,hv);
          }
      }
      __syncthreads();
    }

    // ---------- Stage A: per-stream; elem(s) overlaps gemm(s+1) ----------
    #pragma unroll 1
    for (int s = 0; s < 3; ++s){
      const short* Wp = W1hh_s + s*262144;
      f32x4 cold0, cold1;
      if (tt){ cold0 = ldCS(cstWG, s*2+0, tid); cold1 = ldCS(cstWG, s*2+1, tid); }
      else   { cold0 = z4; cold1 = z4; }
      f32x4 acc[2][4];
      #pragma unroll
      for (int rt = 0; rt < 2; ++rt)
        #pragma unroll
        for (int g = 0; g < 4; ++g) acc[rt][g] = ldCP(cpWG, s, w, rt, g, lane);
      short8 fb0[4], fb1[4], fb2[4];
      LDCH(fb0, Wp, 8, 0); LDCH(fb1, Wp, 8, 1);
      #pragma unroll
      for (int kt = 0; kt < 8; ++kt){
        if (kt < 6) LDCH(ROT3(kt+2), Wp, 8, kt+2);
        MMCH(ROT3(kt), h1b + s*8192, kt);
      }
      __syncthreads();   // protect h1b[s] read-before-write
      #pragma unroll
      for (int rt = 0; rt < 2; ++rt){
        f32x4 cold = rt ? cold1 : cold0;
        f32x4 cnew;
        #pragma unroll
        for (int r = 0; r < 4; ++r){
          const int row = rt*16 + lg*4 + r;
          const int tok = (t == 0) ? 0 : tgt[(s*128 + b0 + row)*256 + (t-1)];
          const short* ep = eprojb + (s*130 + tok)*1024;
          float pi = acc[rt][0][r] + frombf(ep[cc]);
          float pf = acc[rt][1][r] + frombf(ep[256+cc]);
          float pg = acc[rt][2][r] + frombf(ep[512+cc]);
          float po = acc[rt][3][r] + frombf(ep[768+cc]);
          float cs = sigf(pf)*cold[r] + sigf(pi)*tanhf_(pg);
          cnew[r] = cs;
          stH(h1b + s*8192, row, cc, tobf(sigf(po)*tanhf_(cs)));
        }
        stCS(cstWG, s*2+rt, tid, cnew);
      }
      // no barrier: next iteration's gemm reads h1b[s+1], disjoint
    }
    __syncthreads();     // h1b[0..2] complete before B reads them

    // ---------- per-stream sequential section ----------
    #pragma unroll 1
    for (int i = 0; i < 3; ++i){
      // ---- Bg: context lstm_c GEMM (K=1024 over [h1_0,h1_1,h1_2,hc])
      {
        f32x4 cold0, cold1;
        if (tt == 0 && i == 0){ cold0 = z4; cold1 = z4; }
        else { cold0 = ldCS(cstWG, 12, tid); cold1 = ldCS(cstWG, 13, tid); }
        f32x4 acc[2][4];
        #pragma unroll
        for (int rt = 0; rt < 2; ++rt)
          #pragma unroll
          for (int g = 0; g < 4; ++g) acc[rt][g] = z4;
        short8 fb0[4], fb1[4], fb2[4];
        LDCH(fb0, Wc_s, 32, 0); LDCH(fb1, Wc_s, 32, 1);
        #pragma unroll
        for (int kt = 0; kt < 32; ++kt){
          if (kt < 30) LDCH(ROT3(kt+2), Wc_s, 32, kt+2);
          const short* ab = (kt < 8) ? h1b : (kt < 16) ? h1b+8192 : (kt < 24) ? h1b+16384 : hcb;
          MMCH(ROT3(kt), ab, kt & 7);
        }
        __syncthreads();
        const float bi = bc_ih[cc]      + bc_hh[cc];
        const float bf = bc_ih[256+cc]  + bc_hh[256+cc];
        const float bg = bc_ih[512+cc]  + bc_hh[512+cc];
        const float bo = bc_ih[768+cc]  + bc_hh[768+cc];
        #pragma unroll
        for (int rt = 0; rt < 2; ++rt){
          f32x4 cold = rt ? cold1 : cold0;
          f32x4 cnew;
          #pragma unroll
          for (int r = 0; r < 4; ++r){
            const int row = rt*16 + lg*4 + r;
            float pi = acc[rt][0][r] + bi;
            float pf = acc[rt][1][r] + bf;
            float pg = acc[rt][2][r] + bg;
            float po = acc[rt][3][r] + bo;
            float cs = sigf(pf)*cold[r] + sigf(pi)*tanhf_(pg);
            cnew[r] = cs;
            stH(hcb, row, cc, tobf(sigf(po)*tanhf_(cs)));
          }
          stCS(cstWG, 12+rt, tid, cnew);
        }
        __syncthreads();
      }
      // ---- Cg: lstm2 GEMM (hc @ W1ihA + h2 @ W1hh), seeded with cpart
      {
        f32x4 cold0, cold1;
        if (tt == 0){ cold0 = z4; cold1 = z4; }
        else { cold0 = ldCS(cstWG, 6+i*2+0, tid); cold1 = ldCS(cstWG, 6+i*2+1, tid); }
        f32x4 acc[2][4];
        #pragma unroll
        for (int rt = 0; rt < 2; ++rt)
          #pragma unroll
          for (int g = 0; g < 4; ++g) acc[rt][g] = ldCP(cpWG, i, w, rt, g, lane);
        const short* WA = W1ihA_s + i*262144;
        const short* WH = W1hh_s  + i*262144;
        short8 fb0[4], fb1[4], fb2[4];
        LDCH(fb0, WA, 8, 0); LDCH(fb1, WA, 8, 1);
        #pragma unroll
        for (int st = 0; st < 16; ++st){
          if (st < 14){
            const int nx = st + 2;
            LDCH(ROT3(nx), (nx < 8) ? WA : WH, 8, nx & 7);
          }
          MMCH(ROT3(st), (st < 8) ? hcb : (h2b + i*8192), st & 7);
        }
        __syncthreads();
        const float bi = b1_ih[i*1024+cc]      + b1_hh[i*1024+cc];
        const float bf = b1_ih[i*1024+256+cc]  + b1_hh[i*1024+256+cc];
        const float bg = b1_ih[i*1024+512+cc]  + b1_hh[i*1024+512+cc];
        const float bo = b1_ih[i*1024+768+cc]  + b1_hh[i*1024+768+cc];
        #pragma unroll
        for (int rt = 0; rt < 2; ++rt){
          f32x4 cold = rt ? cold1 : cold0;
          f32x4 cnew;
          #pragma unroll
          for (int r = 0; r < 4; ++r){
            const int row = rt*16 + lg*4 + r;
            float pi = acc[rt][0][r] + bi;
            float pf = acc[rt][1][r] + bf;
            float pg = acc[rt][2][r] + bg;
            float po = acc[rt][3][r] + bo;
            float cs = sigf(pf)*cold[r] + sigf(pi)*tanhf_(pg);
            cnew[r] = cs;
            stH(h2b + i*8192, row, cc, tobf(sigf(po)*tanhf_(cs)));
          }
          stCS(cstWG, 6+i*2+rt, tid, cnew);
        }
        __syncthreads();
      }
      // ---- DEg: D GEMM (h1 @ W1hh, seeded with cpart) + E GEMM ((h1+h2)@Wout)
      {
        f32x4 cold0 = ldCS(cstWG, i*2+0, tid);   // always written earlier this tt
        f32x4 cold1 = ldCS(cstWG, i*2+1, tid);
        f32x4 acc[2][4];
        #pragma unroll
        for (int rt = 0; rt < 2; ++rt)
          #pragma unroll
          for (int g = 0; g < 4; ++g) acc[rt][g] = ldCP(cpWG, i, w, rt, g, lane);
        f32x4 e0 = z4, e1 = z4;
        const short* WH = W1hh_s + i*262144;
        const short* WO = Wout_s + i*36864;
        short8 fb0[4], fb1[4], fb2[4];
        short8 eb0, eb1, eb2;
        LDCH(fb0, WH, 8, 0); LDCH(fb1, WH, 8, 1);
        if (w < 9){ eb0 = ldB(WO, w, 8, 0, lane); eb1 = ldB(WO, w, 8, 1, lane); }
        #pragma unroll
        for (int kt = 0; kt < 8; ++kt){
          if (kt < 6){
            LDCH(ROT3(kt+2), WH, 8, kt+2);
            if (w < 9) ROTE3(kt+2) = ldB(WO, w, 8, kt+2, lane);
          }
          short8 a0_ = ldA(h1b + i*8192, 0, kt*32, lane);
          short8 a1_ = ldA(h1b + i*8192, 1, kt*32, lane);
          short8* cb = ROT3(kt);
          acc[0][0]=MFMA16(a0_,cb[0],acc[0][0]); acc[1][0]=MFMA16(a1_,cb[0],acc[1][0]);
          acc[0][1]=MFMA16(a0_,cb[1],acc[0][1]); acc[1][1]=MFMA16(a1_,cb[1],acc[1][1]);
          acc[0][2]=MFMA16(a0_,cb[2],acc[0][2]); acc[1][2]=MFMA16(a1_,cb[2],acc[1][2]);
          acc[0][3]=MFMA16(a0_,cb[3],acc[0][3]); acc[1][3]=MFMA16(a1_,cb[3],acc[1][3]);
          if (w < 9){
            short8 ebc = ROTE3(kt);
            short8 b0f = ldA(h2b + i*8192, 0, kt*32, lane);
            short8 b1f = ldA(h2b + i*8192, 1, kt*32, lane);
            e0 = MFMA16(a0_, ebc, e0);  e0 = MFMA16(b0f, ebc, e0);
            e1 = MFMA16(a1_, ebc, e1);  e1 = MFMA16(b1f, ebc, e1);
          }
        }
        __syncthreads();
        // DEe: teacher-forced lstm1 update + logits store
        #pragma unroll
        for (int rt = 0; rt < 2; ++rt){
          f32x4 cold = rt ? cold1 : cold0;
          f32x4 cnew;
          #pragma unroll
          for (int r = 0; r < 4; ++r){
            const int row = rt*16 + lg*4 + r;
            const int tok = tgt[(i*128 + b0 + row)*256 + t];
            const short* ep = eprojb + (i*130 + tok)*1024;
            float pi = acc[rt][0][r] + frombf(ep[cc]);
            float pf = acc[rt][1][r] + frombf(ep[256+cc]);
            float pg = acc[rt][2][r] + frombf(ep[512+cc]);
            float po = acc[rt][3][r] + frombf(ep[768+cc]);
            float cs = sigf(pf)*cold[r] + sigf(pi)*tanhf_(pg);
            cnew[r] = cs;
            stH(h1b + i*8192, row, cc, tobf(sigf(po)*tanhf_(cs)));
          }
          stCS(cstWG, i*2+rt, tid, cnew);
        }
        if (w < 8){
          const int v = w*16 + l15;
          const float bo = boutp[i*130 + v];
          #pragma unroll
          for (int rt = 0; rt < 2; ++rt)
            #pragma unroll
            for (int r = 0; r < 4; ++r){
              const int row = rt*16 + lg*4 + r;
              outp[(size_t)((i*128 + b0 + row)*256 + t)*130 + v] = (rt ? e1[r] : e0[r]) + bo;
            }
        } else if (w == 8 && l15 < 2){
          const int v = 128 + l15;
          const float bo = boutp[i*130 + v];
          #pragma unroll
          for (int rt = 0; rt < 2; ++rt)
            #pragma unroll
            for (int r = 0; r < 4; ++r){
              const int row = rt*16 + lg*4 + r;
              outp[(size_t)((i*128 + b0 + row)*256 + t)*130 + v] = (rt ? e1[r] : e0[r]) + bo;
            }
        }
        __syncthreads();
      }
    } // i
  } // tt
}

extern "C" void kernel_launch(void* const* d_in, const int* in_sizes, int n_in,
                              void* d_out, int out_size, void* d_ws, size_t ws_size,
                              hipStream_t stream){
  (void)in_sizes; (void)n_in; (void)out_size; (void)ws_size;
  const float* c     = (const float*)d_in[0];
  const int*   tgt   = (const int*)  d_in[1];
  const float* W_hid = (const float*)d_in[3];
  const float* b_hid = (const float*)d_in[4];
  const float* W1_ih = (const float*)d_in[5];
  const float* W1_hh = (const float*)d_in[6];
  const float* b1_ih = (const float*)d_in[7];
  const float* b1_hh = (const float*)d_in[8];
  const float* Wc_ih = (const float*)d_in[9];
  const float* Wc_hh = (const float*)d_in[10];
  const float* bc_ih = (const float*)d_in[11];
  const float* bc_hh = (const float*)d_in[12];
  const float* emb   = (const float*)d_in[13];
  const float* Wout  = (const float*)d_in[14];
  const float* bout  = (const float*)d_in[15];
  float* outp = (float*)d_out;

  short* ws = (short*)d_ws;
  short* W1hh_s  = ws;                 // 3 x 64nt x 8kt tiles
  short* W1ihA_s = ws + 786432;        // W1_ih[:, :256]
  short* W1ihB_s = ws + 1572864;       // W1_ih[:, 256:512]
  short* Wc_s    = ws + 2359296;       // [1024][1024]: ih k<768, hh k>=768
  short* Whid_s  = ws + 3407872;       // [256][256]
  short* Wout_s  = ws + 3473408;       // 3 x [144 pad][256]
  short* eprojb  = ws + 3584000;       // [3][130][1024] bf16
  short* cpart   = ws + 3983360;       // [64 WG][3][16][8][256] bf16 C-frags
  float* cstate  = (float*)((char*)d_ws + 20549632);  // [64 WG][14][1024] f32x4

  for (int s = 0; s < 3; ++s){
    swz_kernel<<<1024,256,0,stream>>>(W1hh_s  + s*262144, W1_hh + s*262144, 256,   0, 1024,  8, 0,  8, 64);
    swz_kernel<<<1024,256,0,stream>>>(W1ihA_s + s*262144, W1_ih + s*524288, 512,   0, 1024,  8, 0,  8, 64);
    swz_kernel<<<1024,256,0,stream>>>(W1ihB_s + s*262144, W1_ih + s*524288, 512, 256, 1024,  8, 0,  8, 64);
    swz_kernel<<< 144,256,0,stream>>>(Wout_s  + s*36864,  Wout  + s*33280,  256,   0,  130,  8, 0,  8,  9);
  }
  swz_kernel<<<3072,256,0,stream>>>(Wc_s,   Wc_ih, 768, 0, 1024, 32,  0, 24, 64);
  swz_kernel<<<1024,256,0,stream>>>(Wc_s,   Wc_hh, 256, 0, 1024, 32, 24,  8, 64);
  swz_kernel<<< 256,256,0,stream>>>(Whid_s, W_hid, 256, 0,  512,  8,  0,  8, 16);
  eproj_kernel<<<3,1024,0,stream>>>(emb, b1_ih, b1_hh, W1ihA_s, eprojb);

  rnn_main<<<dim3(4,16),1024,0,stream>>>(c, tgt, b_hid, b1_ih, b1_hh, bc_ih, bc_hh,
                                         bout, eprojb, cpart, cstate,
                                         W1hh_s, W1ihA_s, W1ihB_s,
                                         Wc_s, Whid_s, Wout_s, outp);
}

// Round 8
// 4824.793 us; speedup vs baseline: 2.6291x; 1.6493x over previous
//
#include <hip/hip_runtime.h>
#include <hip/hip_bf16.h>

typedef float  f32x4  __attribute__((ext_vector_type(4)));
typedef short  short8 __attribute__((ext_vector_type(8)));
typedef short  bf4    __attribute__((ext_vector_type(4)));

#define MFMA16(a,b,c) __builtin_amdgcn_mfma_f32_16x16x32_bf16((a),(b),(c),0,0,0)

__device__ __forceinline__ short tobf(float f){
  unsigned u = __float_as_uint(f);
  u += 0x7fffu + ((u >> 16) & 1u);
  return (short)(u >> 16);
}
__device__ __forceinline__ float frombf(short s){
  return __uint_as_float(((unsigned)(unsigned short)s) << 16);
}
__device__ __forceinline__ float sigf(float x){
  return 1.f / (1.f + __expf(-x));
}
__device__ __forceinline__ float tanhf_(float x){
  float ax = fabsf(x);
  float e  = __expf(-2.f * ax);
  float t  = (1.f - e) / (1.f + e);
  return x >= 0.f ? t : -t;
}
__device__ __forceinline__ bf4 pack4(f32x4 v){
  bf4 r; r[0]=tobf(v[0]); r[1]=tobf(v[1]); r[2]=tobf(v[2]); r[3]=tobf(v[3]); return r;
}

// LDS h-tile: [32 rows][256 cols] bf16, XOR-swizzled 16B slots (G4).
__device__ __forceinline__ int hoff(int row, int col){
  return (row*512 + col*2) ^ ((row & 7) << 4);
}
__device__ __forceinline__ void stH(short* buf, int row, int col, short v){
  *(short*)((char*)buf + hoff(row,col)) = v;
}
// A-fragment (16x32 tile): lane holds A[row=l&15][k0 + (l>>4)*8 + j]
__device__ __forceinline__ short8 ldA(const short* buf, int rt, int k0, int lane){
  int row = rt*16 + (lane & 15);
  int off = (row*512 + (k0 + ((lane>>4)<<3))*2) ^ ((row & 7) << 4);
  return *(const short8*)((const char*)buf + off);
}
// cpart C-fragment layout: per WG [s][w][rt*4+g][lane*4 + r] bf16
__device__ __forceinline__ short* cpPtr(short* cp, int s, int w, int rt, int g, int lane){
  return cp + (((s*16 + w)*8 + rt*4 + g) << 8) + (lane << 2);
}
__device__ __forceinline__ f32x4 ldCP(const short* cp, int s, int w, int rt, int g, int lane){
  bf4 v = *(const bf4*)(cp + (((s*16 + w)*8 + rt*4 + g) << 8) + (lane << 2));
  f32x4 r; r[0]=frombf(v[0]); r[1]=frombf(v[1]); r[2]=frombf(v[2]); r[3]=frombf(v[3]);
  return r;
}
// cell-state slices in global ws: per WG 14 slices x 1024 threads x f32x4
__device__ __forceinline__ f32x4 ldCS(const float* b, int sl, int tid){
  return *(const f32x4*)(b + sl*4096 + tid*4);
}
__device__ __forceinline__ void stCS(float* b, int sl, int tid, f32x4 v){
  *(f32x4*)(b + sl*4096 + tid*4) = v;
}

// One K=256 GEMM segment: acc[2][4] += A(32x256 LDS) @ W-frags (4 gate tiles
// for wave w). Depth-3 static-rotation global prefetch (12 loads in flight).
__device__ __forceinline__ void gemm256(f32x4 (&acc)[2][4], const short* __restrict__ W,
                                        int KT, int kt0, const short* __restrict__ A,
                                        int lane, int w){
  const short* w0 = W + (((     w)*KT + kt0)*64 + lane)*8;
  const short* w1 = W + (((16 + w)*KT + kt0)*64 + lane)*8;
  const short* w2 = W + (((32 + w)*KT + kt0)*64 + lane)*8;
  const short* w3 = W + (((48 + w)*KT + kt0)*64 + lane)*8;
  short8 b0[4], b1[4], b2[4];
#define GLD(B,K) do{ (B)[0]=*(const short8*)(w0+(K)*512); (B)[1]=*(const short8*)(w1+(K)*512); \
                     (B)[2]=*(const short8*)(w2+(K)*512); (B)[3]=*(const short8*)(w3+(K)*512);}while(0)
#define GMM(B,K) do{ short8 a0_=ldA(A,0,(K)*32,lane); short8 a1_=ldA(A,1,(K)*32,lane); \
  acc[0][0]=MFMA16(a0_,(B)[0],acc[0][0]); acc[1][0]=MFMA16(a1_,(B)[0],acc[1][0]); \
  acc[0][1]=MFMA16(a0_,(B)[1],acc[0][1]); acc[1][1]=MFMA16(a1_,(B)[1],acc[1][1]); \
  acc[0][2]=MFMA16(a0_,(B)[2],acc[0][2]); acc[1][2]=MFMA16(a1_,(B)[2],acc[1][2]); \
  acc[0][3]=MFMA16(a0_,(B)[3],acc[0][3]); acc[1][3]=MFMA16(a1_,(B)[3],acc[1][3]);}while(0)
  GLD(b0,0); GLD(b1,1); GLD(b2,2);
  GMM(b0,0); GLD(b0,3);
  GMM(b1,1); GLD(b1,4);
  GMM(b2,2); GLD(b2,5);
  GMM(b0,3); GLD(b0,6);
  GMM(b1,4); GLD(b1,7);
  GMM(b2,5);
  GMM(b0,6);
  GMM(b1,7);
#undef GLD
#undef GMM
}

// Pre-swizzle fp32 weight [N][K] slice into bf16 B-fragments
__global__ void swz_kernel(short* __restrict__ dst, const float* __restrict__ src,
                           int rowStride, int colOff, int Nreal,
                           int KTtot, int kt0, int ktN, int NT){
  int idx = blockIdx.x*256 + threadIdx.x;
  if (idx >= NT*ktN*512) return;
  int j = idx & 7, l = (idx>>3) & 63, tile = idx >> 9;
  int nt = tile / ktN, ktl = tile - nt*ktN;
  int n = nt*16 + (l & 15);
  int k = ktl*32 + ((l>>4)<<3) + j;
  float v = (n < Nreal) ? src[n*rowStride + colOff + k] : 0.f;
  dst[(((nt*KTtot + kt0 + ktl)*64 + l)<<3) + j] = tobf(v);
}

// eprojb layout: [s][v][col 0..255][gate 0..3] bf16 (gate-contig for bf4 gather)
__global__ __launch_bounds__(1024) void eproj_kernel(
    const float* __restrict__ emb, const float* __restrict__ b1_ih,
    const float* __restrict__ b1_hh, const short* __restrict__ W1ihA_s,
    short* __restrict__ eprojb){
  __shared__ short es[36864];     // [144][256] bf16, rows >=130 zero
  const int s = blockIdx.x;
  const int tid = threadIdx.x, lane = tid & 63, w = tid >> 6;
  const int l15 = lane & 15, lg = lane >> 4;
  for (int idx = tid; idx < 36864; idx += 1024){
    int row = idx >> 8, c2 = idx & 255;
    float v = (row < 130) ? emb[(s*130 + row)*256 + c2] : 0.f;
    stH(es, row, c2, tobf(v));
  }
  __syncthreads();
  f32x4 z4 = {0.f,0.f,0.f,0.f};
  for (int rt = 0; rt < 9; ++rt){
    f32x4 acc[4] = {z4, z4, z4, z4};
    #pragma unroll 2
    for (int kt = 0; kt < 8; ++kt){
      short8 a = ldA(es, rt, kt*32, lane);
      #pragma unroll
      for (int q = 0; q < 4; ++q){
        short8 b = *(const short8*)(W1ihA_s + s*262144 + (((w*4+q)*8 + kt)*64 + lane)*8);
        acc[q] = MFMA16(a, b, acc[q]);
      }
    }
    #pragma unroll
    for (int q = 0; q < 4; ++q)
      #pragma unroll
      for (int r = 0; r < 4; ++r){
        int v = rt*16 + lg*4 + r;
        if (v < 130){
          int gc = (w*4 + q)*16 + l15;
          eprojb[(s*130 + v)*1024 + ((gc & 255) << 2) + (gc >> 8)] =
            tobf(acc[q][r] + b1_ih[s*1024 + gc] + b1_hh[s*1024 + gc]);
        }
      }
  }
}

// Main persistent kernel: one WG per (bar, batch-chunk-of-32). 1024 threads,
// 16 waves (4/SIMD forced). Compact rolled phases (I$-resident body), depth-3
// weight prefetch via gemm256; cell state + cpart in global ws.
__global__ __launch_bounds__(1024)
__attribute__((amdgpu_waves_per_eu(4,4))) void rnn_main(
    const float* __restrict__ cbuf, const int* __restrict__ tgt,
    const float* __restrict__ b_hid, const float* __restrict__ b1_ih,
    const float* __restrict__ b1_hh, const float* __restrict__ bc_ih,
    const float* __restrict__ bc_hh, const float* __restrict__ boutp,
    const short* __restrict__ eprojb, short* __restrict__ cpart,
    float* __restrict__ cst,
    const short* __restrict__ W1hh_s, const short* __restrict__ W1ihA_s,
    const short* __restrict__ W1ihB_s, const short* __restrict__ Wc_s,
    const short* __restrict__ Whid_s, const short* __restrict__ Wout_s,
    float* __restrict__ outp)
{
  __shared__ short h1b[3*8192];
  __shared__ short h2b[3*8192];
  __shared__ short hcb[8192];

  const int tid  = threadIdx.x;
  const int lane = tid & 63;
  const int w    = tid >> 6;      // wave 0..15
  const int l15  = lane & 15;
  const int lg   = lane >> 4;
  const int chunk = blockIdx.x;   // 0..3
  const int bar   = blockIdx.y;   // 0..15
  const int b0    = chunk * 32;
  const int cc    = w*16 + l15;
  const int wgid  = bar*4 + chunk;

  short* cpWG  = cpart + wgid*98304;
  float* cstWG = cst + (size_t)wgid*57344;   // 14 slices x 4096 floats
  const f32x4 z4 = {0.f,0.f,0.f,0.f};

  #pragma unroll 1
  for (int tt = 0; tt < 16; ++tt){
    const int t = bar*16 + tt;

    if (tt == 0){
      // stage bf16(c[:,bar]) into h2b[0], bf16(c[:,bar+1]) into h2b[1]
      for (int idx = tid; idx < 8192; idx += 1024){
        int row = idx >> 8, c2 = idx & 255;
        stH(h2b,        row, c2, tobf(cbuf[((b0+row)*17 + bar)*256 + c2]));
        stH(h2b + 8192, row, c2, tobf(cbuf[((b0+row)*17 + bar + 1)*256 + c2]));
      }
      __syncthreads();
      // R2K: h_init pre-activation (c_bar @ W_hid[:256].T), wave w -> nt=w
      f32x4 hi0 = z4, hi1 = z4;
      #pragma unroll
      for (int kt = 0; kt < 8; ++kt){
        short8 a0 = ldA(h2b, 0, kt*32, lane);
        short8 a1 = ldA(h2b, 1, kt*32, lane);
        short8 bb = *(const short8*)(Whid_s + ((w*8 + kt)*64 + lane)*8);
        hi0 = MFMA16(a0, bb, hi0);  hi1 = MFMA16(a1, bb, hi1);
      }
      // R4: cpart[s] = c_t @ W1_ih[s][:,256:].T -> global ws (C-frag layout)
      #pragma unroll 1
      for (int s = 0; s < 3; ++s){
        f32x4 acc[2][4];
        #pragma unroll
        for (int rt = 0; rt < 2; ++rt)
          #pragma unroll
          for (int g = 0; g < 4; ++g) acc[rt][g] = z4;
        gemm256(acc, W1ihB_s + s*262144, 8, 0, h2b + 8192, lane, w);
        #pragma unroll
        for (int rt = 0; rt < 2; ++rt)
          #pragma unroll
          for (int g = 0; g < 4; ++g)
            *(bf4*)cpPtr(cpWG, s, w, rt, g, lane) = pack4(acc[rt][g]);
      }
      __syncthreads();
      // h_init into all 7 h-buffers (clobbers staging)
      {
        float bh = b_hid[cc];
        #pragma unroll
        for (int rt = 0; rt < 2; ++rt)
          #pragma unroll
          for (int r = 0; r < 4; ++r){
            int row = rt*16 + lg*4 + r;
            short hv = tobf(tanhf_((rt ? hi1[r] : hi0[r]) + bh));
            stH(h1b,       row,cc,hv); stH(h1b+8192, row,cc,hv); stH(h1b+16384,row,cc,hv);
            stH(h2b,       row,cc,hv); stH(h2b+8192, row,cc,hv); stH(h2b+16384,row,cc,hv);
            stH(hcb,       row,cc,hv);
          }
      }
      __syncthreads();
    }

    // ---------- Stage A: per-stream; elem(s) overlaps gemm(s+1) ----------
    #pragma unroll 1
    for (int s = 0; s < 3; ++s){
      f32x4 cold0, cold1;
      if (tt){ cold0 = ldCS(cstWG, s*2+0, tid); cold1 = ldCS(cstWG, s*2+1, tid); }
      else   { cold0 = z4; cold1 = z4; }
      f32x4 acc[2][4];
      #pragma unroll
      for (int rt = 0; rt < 2; ++rt)
        #pragma unroll
        for (int g = 0; g < 4; ++g) acc[rt][g] = ldCP(cpWG, s, w, rt, g, lane);
      gemm256(acc, W1hh_s + s*262144, 8, 0, h1b + s*8192, lane, w);
      __syncthreads();   // protect h1b[s] read-before-write
      #pragma unroll
      for (int rt = 0; rt < 2; ++rt){
        f32x4 cold = rt ? cold1 : cold0;
        f32x4 cnew;
        #pragma unroll
        for (int r = 0; r < 4; ++r){
          const int row = rt*16 + lg*4 + r;
          const int tok = (t == 0) ? 0 : tgt[(s*128 + b0 + row)*256 + (t-1)];
          bf4 e4 = *(const bf4*)(eprojb + (size_t)(s*130 + tok)*1024 + cc*4);
          float pi = acc[rt][0][r] + frombf(e4[0]);
          float pf = acc[rt][1][r] + frombf(e4[1]);
          float pg = acc[rt][2][r] + frombf(e4[2]);
          float po = acc[rt][3][r] + frombf(e4[3]);
          float cs = sigf(pf)*cold[r] + sigf(pi)*tanhf_(pg);
          cnew[r] = cs;
          stH(h1b + s*8192, row, cc, tobf(sigf(po)*tanhf_(cs)));
        }
        stCS(cstWG, s*2+rt, tid, cnew);
      }
      // no barrier: next iteration's gemm reads h1b[s+1], disjoint
    }
    __syncthreads();     // h1b[0..2] complete before B reads them

    // ---------- per-stream sequential section ----------
    #pragma unroll 1
    for (int i = 0; i < 3; ++i){
      // ---- Bg: context lstm_c GEMM (K=1024 over [h1_0,h1_1,h1_2,hc])
      {
        f32x4 cold0, cold1;
        if (tt == 0 && i == 0){ cold0 = z4; cold1 = z4; }
        else { cold0 = ldCS(cstWG, 12, tid); cold1 = ldCS(cstWG, 13, tid); }
        f32x4 acc[2][4];
        #pragma unroll
        for (int rt = 0; rt < 2; ++rt)
          #pragma unroll
          for (int g = 0; g < 4; ++g) acc[rt][g] = z4;
        #pragma unroll 1
        for (int seg = 0; seg < 4; ++seg){
          const short* Ax = (seg==0) ? h1b : (seg==1) ? (h1b+8192)
                           : (seg==2) ? (h1b+16384) : hcb;
          gemm256(acc, Wc_s, 32, seg*8, Ax, lane, w);
        }
        __syncthreads();
        const float bi = bc_ih[cc]      + bc_hh[cc];
        const float bf = bc_ih[256+cc]  + bc_hh[256+cc];
        const float bg = bc_ih[512+cc]  + bc_hh[512+cc];
        const float bo = bc_ih[768+cc]  + bc_hh[768+cc];
        #pragma unroll
        for (int rt = 0; rt < 2; ++rt){
          f32x4 cold = rt ? cold1 : cold0;
          f32x4 cnew;
          #pragma unroll
          for (int r = 0; r < 4; ++r){
            const int row = rt*16 + lg*4 + r;
            float cs = sigf(acc[rt][1][r] + bf)*cold[r]
                     + sigf(acc[rt][0][r] + bi)*tanhf_(acc[rt][2][r] + bg);
            cnew[r] = cs;
            stH(hcb, row, cc, tobf(sigf(acc[rt][3][r] + bo)*tanhf_(cs)));
          }
          stCS(cstWG, 12+rt, tid, cnew);
        }
        __syncthreads();
      }
      // ---- Cg: lstm2 GEMM (hc @ W1ihA + h2 @ W1hh), seeded with cpart
      {
        f32x4 cold0, cold1;
        if (tt == 0){ cold0 = z4; cold1 = z4; }
        else { cold0 = ldCS(cstWG, 6+i*2+0, tid); cold1 = ldCS(cstWG, 6+i*2+1, tid); }
        f32x4 acc[2][4];
        #pragma unroll
        for (int rt = 0; rt < 2; ++rt)
          #pragma unroll
          for (int g = 0; g < 4; ++g) acc[rt][g] = ldCP(cpWG, i, w, rt, g, lane);
        #pragma unroll 1
        for (int seg = 0; seg < 2; ++seg){
          const short* Wx = seg ? (W1hh_s + i*262144) : (W1ihA_s + i*262144);
          const short* Ax = seg ? (h2b + i*8192) : hcb;
          gemm256(acc, Wx, 8, 0, Ax, lane, w);
        }
        __syncthreads();
        const float bi = b1_ih[i*1024+cc]      + b1_hh[i*1024+cc];
        const float bf = b1_ih[i*1024+256+cc]  + b1_hh[i*1024+256+cc];
        const float bg = b1_ih[i*1024+512+cc]  + b1_hh[i*1024+512+cc];
        const float bo = b1_ih[i*1024+768+cc]  + b1_hh[i*1024+768+cc];
        #pragma unroll
        for (int rt = 0; rt < 2; ++rt){
          f32x4 cold = rt ? cold1 : cold0;
          f32x4 cnew;
          #pragma unroll
          for (int r = 0; r < 4; ++r){
            const int row = rt*16 + lg*4 + r;
            float cs = sigf(acc[rt][1][r] + bf)*cold[r]
                     + sigf(acc[rt][0][r] + bi)*tanhf_(acc[rt][2][r] + bg);
            cnew[r] = cs;
            stH(h2b + i*8192, row, cc, tobf(sigf(acc[rt][3][r] + bo)*tanhf_(cs)));
          }
          stCS(cstWG, 6+i*2+rt, tid, cnew);
        }
        __syncthreads();
      }
      // ---- DEg: D GEMM (h1 @ W1hh, seeded with cpart) + E GEMM ((h1+h2)@Wout)
      {
        f32x4 cold0 = ldCS(cstWG, i*2+0, tid);
        f32x4 cold1 = ldCS(cstWG, i*2+1, tid);
        f32x4 acc[2][4];
        #pragma unroll
        for (int rt = 0; rt < 2; ++rt)
          #pragma unroll
          for (int g = 0; g < 4; ++g) acc[rt][g] = ldCP(cpWG, i, w, rt, g, lane);
        f32x4 e0 = z4, e1 = z4;
        const short* WH = W1hh_s + i*262144;
        const short* wh0 = WH + (((     w)*8)*64 + lane)*8;
        const short* wh1 = WH + (((16+w)*8)*64 + lane)*8;
        const short* wh2 = WH + (((32+w)*8)*64 + lane)*8;
        const short* wh3 = WH + (((48+w)*8)*64 + lane)*8;
        const short* wo  = Wout_s + i*36864 + ((w*8)*64 + lane)*8;
        const short* h1p = h1b + i*8192;
        const short* h2p = h2b + i*8192;
        short8 hb0[4], hb1[4], ebA, ebB;
#define DLD(B,K) do{ (B)[0]=*(const short8*)(wh0+(K)*512); (B)[1]=*(const short8*)(wh1+(K)*512); \
                     (B)[2]=*(const short8*)(wh2+(K)*512); (B)[3]=*(const short8*)(wh3+(K)*512);}while(0)
#define DMM(B,EB,K) do{ \
  short8 a0_=ldA(h1p,0,(K)*32,lane), a1_=ldA(h1p,1,(K)*32,lane); \
  acc[0][0]=MFMA16(a0_,(B)[0],acc[0][0]); acc[1][0]=MFMA16(a1_,(B)[0],acc[1][0]); \
  acc[0][1]=MFMA16(a0_,(B)[1],acc[0][1]); acc[1][1]=MFMA16(a1_,(B)[1],acc[1][1]); \
  acc[0][2]=MFMA16(a0_,(B)[2],acc[0][2]); acc[1][2]=MFMA16(a1_,(B)[2],acc[1][2]); \
  acc[0][3]=MFMA16(a0_,(B)[3],acc[0][3]); acc[1][3]=MFMA16(a1_,(B)[3],acc[1][3]); \
  if (w < 9){ short8 f0_=ldA(h2p,0,(K)*32,lane), f1_=ldA(h2p,1,(K)*32,lane); \
    e0=MFMA16(a0_,(EB),e0); e0=MFMA16(f0_,(EB),e0); \
    e1=MFMA16(a1_,(EB),e1); e1=MFMA16(f1_,(EB),e1); }}while(0)
        DLD(hb0,0); DLD(hb1,1);
        if (w < 9){ ebA = *(const short8*)(wo); ebB = *(const short8*)(wo+512); }
        DMM(hb0,ebA,0); DLD(hb0,2); if (w<9) ebA = *(const short8*)(wo+2*512);
        DMM(hb1,ebB,1); DLD(hb1,3); if (w<9) ebB = *(const short8*)(wo+3*512);
        DMM(hb0,ebA,2); DLD(hb0,4); if (w<9) ebA = *(const short8*)(wo+4*512);
        DMM(hb1,ebB,3); DLD(hb1,5); if (w<9) ebB = *(const short8*)(wo+5*512);
        DMM(hb0,ebA,4); DLD(hb0,6); if (w<9) ebA = *(const short8*)(wo+6*512);
        DMM(hb1,ebB,5); DLD(hb1,7); if (w<9) ebB = *(const short8*)(wo+7*512);
        DMM(hb0,ebA,6);
        DMM(hb1,ebB,7);
#undef DLD
#undef DMM
        __syncthreads();
        // DEe: teacher-forced lstm1 update + logits store
        #pragma unroll
        for (int rt = 0; rt < 2; ++rt){
          f32x4 cold = rt ? cold1 : cold0;
          f32x4 cnew;
          #pragma unroll
          for (int r = 0; r < 4; ++r){
            const int row = rt*16 + lg*4 + r;
            const int tok = tgt[(i*128 + b0 + row)*256 + t];
            bf4 e4 = *(const bf4*)(eprojb + (size_t)(i*130 + tok)*1024 + cc*4);
            float pi = acc[rt][0][r] + frombf(e4[0]);
            float pf = acc[rt][1][r] + frombf(e4[1]);
            float pg = acc[rt][2][r] + frombf(e4[2]);
            float po = acc[rt][3][r] + frombf(e4[3]);
            float cs = sigf(pf)*cold[r] + sigf(pi)*tanhf_(pg);
            cnew[r] = cs;
            stH(h1b + i*8192, row, cc, tobf(sigf(po)*tanhf_(cs)));
          }
          stCS(cstWG, i*2+rt, tid, cnew);
        }
        if (w < 8){
          const int v = w*16 + l15;
          const float bo = boutp[i*130 + v];
          #pragma unroll
          for (int rt = 0; rt < 2; ++rt)
            #pragma unroll
            for (int r = 0; r < 4; ++r){
              const int row = rt*16 + lg*4 + r;
              outp[(size_t)((i*128 + b0 + row)*256 + t)*130 + v] = (rt ? e1[r] : e0[r]) + bo;
            }
        } else if (w == 8 && l15 < 2){
          const int v = 128 + l15;
          const float bo = boutp[i*130 + v];
          #pragma unroll
          for (int rt = 0; rt < 2; ++rt)
            #pragma unroll
            for (int r = 0; r < 4; ++r){
              const int row = rt*16 + lg*4 + r;
              outp[(size_t)((i*128 + b0 + row)*256 + t)*130 + v] = (rt ? e1[r] : e0[r]) + bo;
            }
        }
        __syncthreads();
      }
    } // i
  } // tt
}

extern "C" void kernel_launch(void* const* d_in, const int* in_sizes, int n_in,
                              void* d_out, int out_size, void* d_ws, size_t ws_size,
                              hipStream_t stream){
  (void)in_sizes; (void)n_in; (void)out_size; (void)ws_size;
  const float* c     = (const float*)d_in[0];
  const int*   tgt   = (const int*)  d_in[1];
  const float* W_hid = (const float*)d_in[3];
  const float* b_hid = (const float*)d_in[4];
  const float* W1_ih = (const float*)d_in[5];
  const float* W1_hh = (const float*)d_in[6];
  const float* b1_ih = (const float*)d_in[7];
  const float* b1_hh = (const float*)d_in[8];
  const float* Wc_ih = (const float*)d_in[9];
  const float* Wc_hh = (const float*)d_in[10];
  const float* bc_ih = (const float*)d_in[11];
  const float* bc_hh = (const float*)d_in[12];
  const float* emb   = (const float*)d_in[13];
  const float* Wout  = (const float*)d_in[14];
  const float* bout  = (const float*)d_in[15];
  float* outp = (float*)d_out;

  short* ws = (short*)d_ws;
  short* W1hh_s  = ws;                 // 3 x 64nt x 8kt tiles
  short* W1ihA_s = ws + 786432;        // W1_ih[:, :256]
  short* W1ihB_s = ws + 1572864;       // W1_ih[:, 256:512]
  short* Wc_s    = ws + 2359296;       // [1024][1024]: ih k<768, hh k>=768
  short* Whid_s  = ws + 3407872;       // [256][256]
  short* Wout_s  = ws + 3473408;       // 3 x [144 pad][256]
  short* eprojb  = ws + 3584000;       // [3][130][256][4] bf16
  short* cpart   = ws + 3983360;       // [64 WG][3][16][8][256] bf16 C-frags
  float* cstate  = (float*)((char*)d_ws + 20549632);  // [64 WG][14][1024] f32x4

  for (int s = 0; s < 3; ++s){
    swz_kernel<<<1024,256,0,stream>>>(W1hh_s  + s*262144, W1_hh + s*262144, 256,   0, 1024,  8, 0,  8, 64);
    swz_kernel<<<1024,256,0,stream>>>(W1ihA_s + s*262144, W1_ih + s*524288, 512,   0, 1024,  8, 0,  8, 64);
    swz_kernel<<<1024,256,0,stream>>>(W1ihB_s + s*262144, W1_ih + s*524288, 512, 256, 1024,  8, 0,  8, 64);
    swz_kernel<<< 144,256,0,stream>>>(Wout_s  + s*36864,  Wout  + s*33280,  256,   0,  130,  8, 0,  8,  9);
  }
  swz_kernel<<<3072,256,0,stream>>>(Wc_s,   Wc_ih, 768, 0, 1024, 32,  0, 24, 64);
  swz_kernel<<<1024,256,0,stream>>>(Wc_s,   Wc_hh, 256, 0, 1024, 32, 24,  8, 64);
  swz_kernel<<< 256,256,0,stream>>>(Whid_s, W_hid, 256, 0,  512,  8,  0,  8, 16);
  eproj_kernel<<<3,1024,0,stream>>>(emb, b1_ih, b1_hh, W1ihA_s, eprojb);

  rnn_main<<<dim3(4,16),1024,0,stream>>>(c, tgt, b_hid, b1_ih, b1_hh, bc_ih, bc_hh,
                                         bout, eprojb, cpart, cstate,
                                         W1hh_s, W1ihA_s, W1ihB_s,
                                         Wc_s, Whid_s, Wout_s, outp);
}

// Round 9
// 3094.098 us; speedup vs baseline: 4.0996x; 1.5594x over previous
//
#include <hip/hip_runtime.h>
#include <hip/hip_bf16.h>

typedef float  f32x4  __attribute__((ext_vector_type(4)));
typedef short  short8 __attribute__((ext_vector_type(8)));
typedef short  bf4    __attribute__((ext_vector_type(4)));

#define MFMA16(a,b,c) __builtin_amdgcn_mfma_f32_16x16x32_bf16((a),(b),(c),0,0,0)

__device__ __forceinline__ short tobf(float f){
  unsigned u = __float_as_uint(f);
  u += 0x7fffu + ((u >> 16) & 1u);
  return (short)(u >> 16);
}
__device__ __forceinline__ float frombf(short s){
  return __uint_as_float(((unsigned)(unsigned short)s) << 16);
}
__device__ __forceinline__ float sigf(float x){
  return 1.f / (1.f + __expf(-x));
}
__device__ __forceinline__ float tanhf_(float x){
  float ax = fabsf(x);
  float e  = __expf(-2.f * ax);
  float t  = (1.f - e) / (1.f + e);
  return x >= 0.f ? t : -t;
}
__device__ __forceinline__ bf4 pack4(f32x4 v){
  bf4 r; r[0]=tobf(v[0]); r[1]=tobf(v[1]); r[2]=tobf(v[2]); r[3]=tobf(v[3]); return r;
}

// LDS h-tile: [16 rows][256 cols] bf16, XOR-swizzled 16B slots (G4).
__device__ __forceinline__ int hoff(int row, int col){
  return (row*512 + col*2) ^ ((row & 7) << 4);
}
__device__ __forceinline__ void stH(short* buf, int row, int col, short v){
  *(short*)((char*)buf + hoff(row,col)) = v;
}
// A-fragment (16x32 tile): lane holds A[row=l&15][k0 + (l>>4)*8 + j]
__device__ __forceinline__ short8 ldA(const short* buf, int k0, int lane){
  int row = lane & 15;
  int off = (row*512 + (k0 + ((lane>>4)<<3))*2) ^ ((row & 7) << 4);
  return *(const short8*)((const char*)buf + off);
}
// cpart C-fragment layout: per WG [s][w][g][lane*4 + r] bf16
__device__ __forceinline__ short* cpPtr(short* cp, int s, int w, int g, int lane){
  return cp + (((s*16 + w)*4 + g) << 8) + (lane << 2);
}
__device__ __forceinline__ f32x4 ldCP(const short* cp, int s, int w, int g, int lane){
  bf4 v = *(const bf4*)(cp + (((s*16 + w)*4 + g) << 8) + (lane << 2));
  f32x4 r; r[0]=frombf(v[0]); r[1]=frombf(v[1]); r[2]=frombf(v[2]); r[3]=frombf(v[3]);
  return r;
}
// cell-state slices in global ws: per WG 7 slices x 1024 threads x f32x4
__device__ __forceinline__ f32x4 ldCS(const float* b, int sl, int tid){
  return *(const f32x4*)(b + sl*4096 + tid*4);
}
__device__ __forceinline__ void stCS(float* b, int sl, int tid, f32x4 v){
  *(f32x4*)(b + sl*4096 + tid*4) = v;
}

// One K=256 GEMM segment (M=16): acc[4] += A(16x256 LDS) @ W-frags (4 gate
// tiles for wave w). Depth-4 static-rotation global prefetch (16 in flight).
__device__ __forceinline__ void gemm256(f32x4 (&acc)[4], const short* __restrict__ W,
                                        int KT, int kt0, const short* __restrict__ A,
                                        int lane, int w){
  const short* w0 = W + (((     w)*KT + kt0)*64 + lane)*8;
  const short* w1 = W + (((16 + w)*KT + kt0)*64 + lane)*8;
  const short* w2 = W + (((32 + w)*KT + kt0)*64 + lane)*8;
  const short* w3 = W + (((48 + w)*KT + kt0)*64 + lane)*8;
  short8 b0[4], b1[4], b2[4], b3[4];
#define GLD(B,K) do{ (B)[0]=*(const short8*)(w0+(K)*512); (B)[1]=*(const short8*)(w1+(K)*512); \
                     (B)[2]=*(const short8*)(w2+(K)*512); (B)[3]=*(const short8*)(w3+(K)*512);}while(0)
#define GMM(B,K) do{ short8 a0_=ldA(A,(K)*32,lane); \
  acc[0]=MFMA16(a0_,(B)[0],acc[0]); acc[1]=MFMA16(a0_,(B)[1],acc[1]); \
  acc[2]=MFMA16(a0_,(B)[2],acc[2]); acc[3]=MFMA16(a0_,(B)[3],acc[3]);}while(0)
  GLD(b0,0); GLD(b1,1); GLD(b2,2); GLD(b3,3);
  GMM(b0,0); GLD(b0,4);
  GMM(b1,1); GLD(b1,5);
  GMM(b2,2); GLD(b2,6);
  GMM(b3,3); GLD(b3,7);
  GMM(b0,4);
  GMM(b1,5);
  GMM(b2,6);
  GMM(b3,7);
#undef GLD
#undef GMM
}

// Pre-swizzle fp32 weight [N][K] slice into bf16 B-fragments
__global__ void swz_kernel(short* __restrict__ dst, const float* __restrict__ src,
                           int rowStride, int colOff, int Nreal,
                           int KTtot, int kt0, int ktN, int NT){
  int idx = blockIdx.x*256 + threadIdx.x;
  if (idx >= NT*ktN*512) return;
  int j = idx & 7, l = (idx>>3) & 63, tile = idx >> 9;
  int nt = tile / ktN, ktl = tile - nt*ktN;
  int n = nt*16 + (l & 15);
  int k = ktl*32 + ((l>>4)<<3) + j;
  float v = (n < Nreal) ? src[n*rowStride + colOff + k] : 0.f;
  dst[(((nt*KTtot + kt0 + ktl)*64 + l)<<3) + j] = tobf(v);
}

// eprojb layout: [s][v][col 0..255][gate 0..3] bf16 (gate-contig for bf4 gather)
__global__ __launch_bounds__(1024) void eproj_kernel(
    const float* __restrict__ emb, const float* __restrict__ b1_ih,
    const float* __restrict__ b1_hh, const short* __restrict__ W1ihA_s,
    short* __restrict__ eprojb){
  __shared__ short es[36864];     // [144][256] bf16, rows >=130 zero
  const int s = blockIdx.x;
  const int tid = threadIdx.x, lane = tid & 63, w = tid >> 6;
  const int l15 = lane & 15, lg = lane >> 4;
  for (int idx = tid; idx < 36864; idx += 1024){
    int row = idx >> 8, c2 = idx & 255;
    float v = (row < 130) ? emb[(s*130 + row)*256 + c2] : 0.f;
    // es uses 32-row-style hoff but rows<144: use plain row*512 variant
    *(short*)((char*)es + ((row*512 + c2*2) ^ ((row & 7) << 4))) = tobf(v);
  }
  __syncthreads();
  f32x4 z4 = {0.f,0.f,0.f,0.f};
  for (int rt = 0; rt < 9; ++rt){
    const short* Arow = es + rt*4096;      // 16-row subtile (rt*16 rows)
    f32x4 acc[4] = {z4, z4, z4, z4};
    #pragma unroll 2
    for (int kt = 0; kt < 8; ++kt){
      short8 a = ldA(Arow, kt*32, lane);
      #pragma unroll
      for (int q = 0; q < 4; ++q){
        short8 b = *(const short8*)(W1ihA_s + s*262144 + (((w*4+q)*8 + kt)*64 + lane)*8);
        acc[q] = MFMA16(a, b, acc[q]);
      }
    }
    #pragma unroll
    for (int q = 0; q < 4; ++q)
      #pragma unroll
      for (int r = 0; r < 4; ++r){
        int v = rt*16 + lg*4 + r;
        if (v < 130){
          int gc = (w*4 + q)*16 + l15;
          eprojb[(s*130 + v)*1024 + ((gc & 255) << 2) + (gc >> 8)] =
            tobf(acc[q][r] + b1_ih[s*1024 + gc] + b1_hh[s*1024 + gc]);
        }
      }
  }
}

// Main persistent kernel: one WG per (bar, batch-chunk-of-16). 128 WGs, 1024
// threads, 16 waves (4/SIMD). M=16 per GEMM; depth-4 weight prefetch.
__global__ __launch_bounds__(1024)
__attribute__((amdgpu_waves_per_eu(4,4))) void rnn_main(
    const float* __restrict__ cbuf, const int* __restrict__ tgt,
    const float* __restrict__ b_hid, const float* __restrict__ b1_ih,
    const float* __restrict__ b1_hh, const float* __restrict__ bc_ih,
    const float* __restrict__ bc_hh, const float* __restrict__ boutp,
    const short* __restrict__ eprojb, short* __restrict__ cpart,
    float* __restrict__ cst,
    const short* __restrict__ W1hh_s, const short* __restrict__ W1ihA_s,
    const short* __restrict__ W1ihB_s, const short* __restrict__ Wc_s,
    const short* __restrict__ Whid_s, const short* __restrict__ Wout_s,
    float* __restrict__ outp)
{
  __shared__ short h1b[3*4096];
  __shared__ short h2b[3*4096];
  __shared__ short hcb[4096];

  const int tid  = threadIdx.x;
  const int lane = tid & 63;
  const int w    = tid >> 6;      // wave 0..15
  const int l15  = lane & 15;
  const int lg   = lane >> 4;
  const int chunk = blockIdx.x;   // 0..7
  const int bar   = blockIdx.y;   // 0..15
  const int b0    = chunk * 16;
  const int cc    = w*16 + l15;
  const int wgid  = bar*8 + chunk;

  short* cpWG  = cpart + wgid*49152;
  float* cstWG = cst + (size_t)wgid*28672;   // 7 slices x 4096 floats
  const f32x4 z4 = {0.f,0.f,0.f,0.f};

  #pragma unroll 1
  for (int tt = 0; tt < 16; ++tt){
    const int t = bar*16 + tt;

    if (tt == 0){
      // stage bf16(c[:,bar]) into h2b[0], bf16(c[:,bar+1]) into h2b[1]
      for (int idx = tid; idx < 4096; idx += 1024){
        int row = idx >> 8, c2 = idx & 255;
        stH(h2b,        row, c2, tobf(cbuf[((b0+row)*17 + bar)*256 + c2]));
        stH(h2b + 4096, row, c2, tobf(cbuf[((b0+row)*17 + bar + 1)*256 + c2]));
      }
      __syncthreads();
      // R2K: h_init pre-activation (c_bar @ W_hid[:256].T), wave w -> nt=w
      f32x4 hi0 = z4;
      #pragma unroll
      for (int kt = 0; kt < 8; ++kt){
        short8 a0 = ldA(h2b, kt*32, lane);
        short8 bb = *(const short8*)(Whid_s + ((w*8 + kt)*64 + lane)*8);
        hi0 = MFMA16(a0, bb, hi0);
      }
      // R4: cpart[s] = c_t @ W1_ih[s][:,256:].T -> global ws (C-frag layout)
      #pragma unroll 1
      for (int s = 0; s < 3; ++s){
        f32x4 acc[4] = {z4, z4, z4, z4};
        gemm256(acc, W1ihB_s + s*262144, 8, 0, h2b + 4096, lane, w);
        #pragma unroll
        for (int g = 0; g < 4; ++g)
          *(bf4*)cpPtr(cpWG, s, w, g, lane) = pack4(acc[g]);
      }
      __syncthreads();
      // h_init into all 7 h-buffers (clobbers staging)
      {
        float bh = b_hid[cc];
        #pragma unroll
        for (int r = 0; r < 4; ++r){
          int row = lg*4 + r;
          short hv = tobf(tanhf_(hi0[r] + bh));
          stH(h1b,       row,cc,hv); stH(h1b+4096, row,cc,hv); stH(h1b+8192,row,cc,hv);
          stH(h2b,       row,cc,hv); stH(h2b+4096, row,cc,hv); stH(h2b+8192,row,cc,hv);
          stH(hcb,       row,cc,hv);
        }
      }
      __syncthreads();
    }

    // ---------- Stage A: per-stream; elem(s) overlaps gemm(s+1) ----------
    #pragma unroll 1
    for (int s = 0; s < 3; ++s){
      f32x4 cold = tt ? ldCS(cstWG, s, tid) : z4;
      f32x4 acc[4];
      #pragma unroll
      for (int g = 0; g < 4; ++g) acc[g] = ldCP(cpWG, s, w, g, lane);
      gemm256(acc, W1hh_s + s*262144, 8, 0, h1b + s*4096, lane, w);
      __syncthreads();   // protect h1b[s] read-before-write
      f32x4 cnew;
      #pragma unroll
      for (int r = 0; r < 4; ++r){
        const int row = lg*4 + r;
        const int tok = (t == 0) ? 0 : tgt[(s*128 + b0 + row)*256 + (t-1)];
        bf4 e4 = *(const bf4*)(eprojb + (size_t)(s*130 + tok)*1024 + cc*4);
        float pi = acc[0][r] + frombf(e4[0]);
        float pf = acc[1][r] + frombf(e4[1]);
        float pg = acc[2][r] + frombf(e4[2]);
        float po = acc[3][r] + frombf(e4[3]);
        float cs = sigf(pf)*cold[r] + sigf(pi)*tanhf_(pg);
        cnew[r] = cs;
        stH(h1b + s*4096, row, cc, tobf(sigf(po)*tanhf_(cs)));
      }
      stCS(cstWG, s, tid, cnew);
      // no barrier: next iteration's gemm reads h1b[s+1], disjoint
    }
    __syncthreads();     // h1b[0..2] complete before B reads them

    // ---------- per-stream sequential section ----------
    #pragma unroll 1
    for (int i = 0; i < 3; ++i){
      // ---- Bg: context lstm_c GEMM (K=1024 over [h1_0,h1_1,h1_2,hc])
      {
        f32x4 cold = (tt == 0 && i == 0) ? z4 : ldCS(cstWG, 6, tid);
        f32x4 acc[4] = {z4, z4, z4, z4};
        #pragma unroll 1
        for (int seg = 0; seg < 4; ++seg){
          const short* Ax = (seg==0) ? h1b : (seg==1) ? (h1b+4096)
                           : (seg==2) ? (h1b+8192) : hcb;
          gemm256(acc, Wc_s, 32, seg*8, Ax, lane, w);
        }
        __syncthreads();
        const float bi = bc_ih[cc]      + bc_hh[cc];
        const float bf = bc_ih[256+cc]  + bc_hh[256+cc];
        const float bg = bc_ih[512+cc]  + bc_hh[512+cc];
        const float bo = bc_ih[768+cc]  + bc_hh[768+cc];
        f32x4 cnew;
        #pragma unroll
        for (int r = 0; r < 4; ++r){
          const int row = lg*4 + r;
          float cs = sigf(acc[1][r] + bf)*cold[r]
                   + sigf(acc[0][r] + bi)*tanhf_(acc[2][r] + bg);
          cnew[r] = cs;
          stH(hcb, row, cc, tobf(sigf(acc[3][r] + bo)*tanhf_(cs)));
        }
        stCS(cstWG, 6, tid, cnew);
        __syncthreads();
      }
      // ---- Cg: lstm2 GEMM (hc @ W1ihA + h2 @ W1hh), seeded with cpart
      {
        f32x4 cold = (tt == 0) ? z4 : ldCS(cstWG, 3+i, tid);
        f32x4 acc[4];
        #pragma unroll
        for (int g = 0; g < 4; ++g) acc[g] = ldCP(cpWG, i, w, g, lane);
        gemm256(acc, W1ihA_s + i*262144, 8, 0, hcb, lane, w);
        gemm256(acc, W1hh_s  + i*262144, 8, 0, h2b + i*4096, lane, w);
        __syncthreads();
        const float bi = b1_ih[i*1024+cc]      + b1_hh[i*1024+cc];
        const float bf = b1_ih[i*1024+256+cc]  + b1_hh[i*1024+256+cc];
        const float bg = b1_ih[i*1024+512+cc]  + b1_hh[i*1024+512+cc];
        const float bo = b1_ih[i*1024+768+cc]  + b1_hh[i*1024+768+cc];
        f32x4 cnew;
        #pragma unroll
        for (int r = 0; r < 4; ++r){
          const int row = lg*4 + r;
          float cs = sigf(acc[1][r] + bf)*cold[r]
                   + sigf(acc[0][r] + bi)*tanhf_(acc[2][r] + bg);
          cnew[r] = cs;
          stH(h2b + i*4096, row, cc, tobf(sigf(acc[3][r] + bo)*tanhf_(cs)));
        }
        stCS(cstWG, 3+i, tid, cnew);
        __syncthreads();
      }
      // ---- DEg: D GEMM (h1 @ W1hh, seeded with cpart) + E GEMM ((h1+h2)@Wout)
      {
        f32x4 cold = ldCS(cstWG, i, tid);
        f32x4 acc[4];
        #pragma unroll
        for (int g = 0; g < 4; ++g) acc[g] = ldCP(cpWG, i, w, g, lane);
        f32x4 e0 = z4;
        const short* WH = W1hh_s + i*262144;
        const short* wh0 = WH + (((     w)*8)*64 + lane)*8;
        const short* wh1 = WH + (((16+w)*8)*64 + lane)*8;
        const short* wh2 = WH + (((32+w)*8)*64 + lane)*8;
        const short* wh3 = WH + (((48+w)*8)*64 + lane)*8;
        const short* wo  = Wout_s + i*36864 + ((w*8)*64 + lane)*8;
        const short* h1p = h1b + i*4096;
        const short* h2p = h2b + i*4096;
        short8 hb0[4], hb1[4], hb2[4], hb3[4], ebA, ebB;
#define DLD(B,K) do{ (B)[0]=*(const short8*)(wh0+(K)*512); (B)[1]=*(const short8*)(wh1+(K)*512); \
                     (B)[2]=*(const short8*)(wh2+(K)*512); (B)[3]=*(const short8*)(wh3+(K)*512);}while(0)
#define DMM(B,EB,K) do{ \
  short8 a0_=ldA(h1p,(K)*32,lane); \
  acc[0]=MFMA16(a0_,(B)[0],acc[0]); acc[1]=MFMA16(a0_,(B)[1],acc[1]); \
  acc[2]=MFMA16(a0_,(B)[2],acc[2]); acc[3]=MFMA16(a0_,(B)[3],acc[3]); \
  if (w < 9){ short8 f0_=ldA(h2p,(K)*32,lane); \
    e0=MFMA16(a0_,(EB),e0); e0=MFMA16(f0_,(EB),e0); }}while(0)
        DLD(hb0,0); DLD(hb1,1); DLD(hb2,2); DLD(hb3,3);
        if (w < 9){ ebA = *(const short8*)(wo); ebB = *(const short8*)(wo+512); }
        DMM(hb0,ebA,0); DLD(hb0,4); if (w<9) ebA = *(const short8*)(wo+2*512);
        DMM(hb1,ebB,1); DLD(hb1,5); if (w<9) ebB = *(const short8*)(wo+3*512);
        DMM(hb2,ebA,2); DLD(hb2,6); if (w<9) ebA = *(const short8*)(wo+4*512);
        DMM(hb3,ebB,3); DLD(hb3,7); if (w<9) ebB = *(const short8*)(wo+5*512);
        DMM(hb0,ebA,4); if (w<9) ebA = *(const short8*)(wo+6*512);
        DMM(hb1,ebB,5); if (w<9) ebB = *(const short8*)(wo+7*512);
        DMM(hb2,ebA,6);
        DMM(hb3,ebB,7);
#undef DLD
#undef DMM
        __syncthreads();
        // DEe: teacher-forced lstm1 update + logits store
        f32x4 cnew;
        #pragma unroll
        for (int r = 0; r < 4; ++r){
          const int row = lg*4 + r;
          const int tok = tgt[(i*128 + b0 + row)*256 + t];
          bf4 e4 = *(const bf4*)(eprojb + (size_t)(i*130 + tok)*1024 + cc*4);
          float pi = acc[0][r] + frombf(e4[0]);
          float pf = acc[1][r] + frombf(e4[1]);
          float pg = acc[2][r] + frombf(e4[2]);
          float po = acc[3][r] + frombf(e4[3]);
          float cs = sigf(pf)*cold[r] + sigf(pi)*tanhf_(pg);
          cnew[r] = cs;
          stH(h1b + i*4096, row, cc, tobf(sigf(po)*tanhf_(cs)));
        }
        stCS(cstWG, i, tid, cnew);
        if (w < 8){
          const int v = w*16 + l15;
          const float bo = boutp[i*130 + v];
          #pragma unroll
          for (int r = 0; r < 4; ++r){
            const int row = lg*4 + r;
            outp[(size_t)((i*128 + b0 + row)*256 + t)*130 + v] = e0[r] + bo;
          }
        } else if (w == 8 && l15 < 2){
          const int v = 128 + l15;
          const float bo = boutp[i*130 + v];
          #pragma unroll
          for (int r = 0; r < 4; ++r){
            const int row = lg*4 + r;
            outp[(size_t)((i*128 + b0 + row)*256 + t)*130 + v] = e0[r] + bo;
          }
        }
        __syncthreads();
      }
    } // i
  } // tt
}

extern "C" void kernel_launch(void* const* d_in, const int* in_sizes, int n_in,
                              void* d_out, int out_size, void* d_ws, size_t ws_size,
                              hipStream_t stream){
  (void)in_sizes; (void)n_in; (void)out_size; (void)ws_size;
  const float* c     = (const float*)d_in[0];
  const int*   tgt   = (const int*)  d_in[1];
  const float* W_hid = (const float*)d_in[3];
  const float* b_hid = (const float*)d_in[4];
  const float* W1_ih = (const float*)d_in[5];
  const float* W1_hh = (const float*)d_in[6];
  const float* b1_ih = (const float*)d_in[7];
  const float* b1_hh = (const float*)d_in[8];
  const float* Wc_ih = (const float*)d_in[9];
  const float* Wc_hh = (const float*)d_in[10];
  const float* bc_ih = (const float*)d_in[11];
  const float* bc_hh = (const float*)d_in[12];
  const float* emb   = (const float*)d_in[13];
  const float* Wout  = (const float*)d_in[14];
  const float* bout  = (const float*)d_in[15];
  float* outp = (float*)d_out;

  short* ws = (short*)d_ws;
  short* W1hh_s  = ws;                 // 3 x 64nt x 8kt tiles
  short* W1ihA_s = ws + 786432;        // W1_ih[:, :256]
  short* W1ihB_s = ws + 1572864;       // W1_ih[:, 256:512]
  short* Wc_s    = ws + 2359296;       // [1024][1024]: ih k<768, hh k>=768
  short* Whid_s  = ws + 3407872;       // [256][256]
  short* Wout_s  = ws + 3473408;       // 3 x [144 pad][256]
  short* eprojb  = ws + 3584000;       // [3][130][256][4] bf16
  short* cpart   = ws + 3983360;       // [128 WG][3][16][4][256] bf16 C-frags
  float* cstate  = (float*)((char*)d_ws + 20549632);  // [128 WG][7][1024] f32x4

  for (int s = 0; s < 3; ++s){
    swz_kernel<<<1024,256,0,stream>>>(W1hh_s  + s*262144, W1_hh + s*262144, 256,   0, 1024,  8, 0,  8, 64);
    swz_kernel<<<1024,256,0,stream>>>(W1ihA_s + s*262144, W1_ih + s*524288, 512,   0, 1024,  8, 0,  8, 64);
    swz_kernel<<<1024,256,0,stream>>>(W1ihB_s + s*262144, W1_ih + s*524288, 512, 256, 1024,  8, 0,  8, 64);
    swz_kernel<<< 144,256,0,stream>>>(Wout_s  + s*36864,  Wout  + s*33280,  256,   0,  130,  8, 0,  8,  9);
  }
  swz_kernel<<<3072,256,0,stream>>>(Wc_s,   Wc_ih, 768, 0, 1024, 32,  0, 24, 64);
  swz_kernel<<<1024,256,0,stream>>>(Wc_s,   Wc_hh, 256, 0, 1024, 32, 24,  8, 64);
  swz_kernel<<< 256,256,0,stream>>>(Whid_s, W_hid, 256, 0,  512,  8,  0,  8, 16);
  eproj_kernel<<<3,1024,0,stream>>>(emb, b1_ih, b1_hh, W1ihA_s, eprojb);

  rnn_main<<<dim3(8,16),1024,0,stream>>>(c, tgt, b_hid, b1_ih, b1_hh, bc_ih, bc_hh,
                                         bout, eprojb, cpart, cstate,
                                         W1hh_s, W1ihA_s, W1ihB_s,
                                         Wc_s, Whid_s, Wout_s, outp);
}